// Round 1
// baseline (1912.330 us; speedup 1.0000x reference)
//
#include <hip/hip_runtime.h>
#include <math.h>

#define TT  2048
#define DIN 1024
#define NH  8
#define DH  128

#define LNT 7.6246189861593985f   // ln(2048)

// ---- workspace layout (float offsets) ----
#define OFF_U      0u
#define OFF_C      2097152u        // C = U U^T  [T,T], dead after phase1
#define OFF_Y      2097152u        // y [H,T,DH] overlays C
#define OFF_YCAT   4194304u        // ycat [T,1024] overlays C upper half
#define OFF_Q      6291456u
#define OFF_K      8388608u
#define OFF_V      10485760u
#define OFF_AP     12582912u       // AP [T,T]
#define OFF_DIVSUM 16777216u
#define OFF_MST    16779264u
#define OFF_LST    16795648u
#define OFF_ENTRAW 16812032u
#define OFF_ENT    16828416u
#define OFF_DEP    16844800u
// total 16861184 floats = 67.4 MB

__device__ __forceinline__ float blockReduceSum256(float v) {
  __shared__ float sh[4];
  #pragma unroll
  for (int m = 1; m < 64; m <<= 1) v += __shfl_xor(v, m, 64);
  if ((threadIdx.x & 63) == 0) sh[threadIdx.x >> 6] = v;
  __syncthreads();
  float r = sh[0] + sh[1] + sh[2] + sh[3];
  __syncthreads();
  return r;
}

// U[t,:] = x[t,:] / max(||x[t,:]||, 1e-12)
__global__ __launch_bounds__(256) void k_rownorm(const float* __restrict__ x,
                                                 float* __restrict__ U) {
  int t = blockIdx.x;
  const float* xr = x + (size_t)t * DIN;
  float ss = 0.f;
  for (int d = threadIdx.x; d < DIN; d += 256) { float v = xr[d]; ss += v * v; }
  ss = blockReduceSum256(ss);
  float inv = 1.f / fmaxf(sqrtf(ss), 1e-12f);
  float* ur = U + (size_t)t * DIN;
  for (int d = threadIdx.x; d < DIN; d += 256) ur[d] = xr[d] * inv;
}

// C[M,N] = A[M,K] * B[N,K]^T   (row-major, dot of A rows with B rows)
#define BM 64
#define BN 64
#define BK 16
#define LDT 20
__global__ __launch_bounds__(256) void k_gemm_nt(const float* __restrict__ A,
                                                 const float* __restrict__ B,
                                                 float* __restrict__ C,
                                                 int M, int N, int Kd) {
  __shared__ __align__(16) float As[BM][LDT];
  __shared__ __align__(16) float Bs[BN][LDT];
  int tid = threadIdx.x;
  int tx = tid & 15, ty = tid >> 4;
  int m0 = blockIdx.y * BM, n0 = blockIdx.x * BN;
  int lrow = tid >> 2;            // 0..63
  int lcol = (tid & 3) << 2;      // 0,4,8,12
  float acc[4][4];
  #pragma unroll
  for (int i = 0; i < 4; i++)
    #pragma unroll
    for (int j = 0; j < 4; j++) acc[i][j] = 0.f;

  for (int k0 = 0; k0 < Kd; k0 += BK) {
    __syncthreads();
    float4 av = *(const float4*)&A[(size_t)(m0 + lrow) * Kd + k0 + lcol];
    float4 bv = *(const float4*)&B[(size_t)(n0 + lrow) * Kd + k0 + lcol];
    *(float4*)&As[lrow][lcol] = av;
    *(float4*)&Bs[lrow][lcol] = bv;
    __syncthreads();
    #pragma unroll
    for (int kk = 0; kk < BK; kk += 4) {
      float4 a4[4], b4[4];
      #pragma unroll
      for (int i = 0; i < 4; i++) a4[i] = *(const float4*)&As[ty * 4 + i][kk];
      #pragma unroll
      for (int j = 0; j < 4; j++) b4[j] = *(const float4*)&Bs[tx * 4 + j][kk];
      #pragma unroll
      for (int i = 0; i < 4; i++)
        #pragma unroll
        for (int j = 0; j < 4; j++)
          acc[i][j] += a4[i].x * b4[j].x + a4[i].y * b4[j].y +
                       a4[i].z * b4[j].z + a4[i].w * b4[j].w;
    }
  }
  #pragma unroll
  for (int i = 0; i < 4; i++)
    #pragma unroll
    for (int j = 0; j < 4; j++)
      C[(size_t)(m0 + ty * 4 + i) * N + n0 + tx * 4 + j] = acc[i][j];
}

// divsum[t] = T - sum_s C[t,s]
__global__ __launch_bounds__(256) void k_divsum(const float* __restrict__ C,
                                                float* __restrict__ divsum) {
  int t = blockIdx.x;
  float s = 0.f;
  for (int j = threadIdx.x; j < TT; j += 256) s += C[(size_t)t * TT + j];
  s = blockReduceSum256(s);
  if (threadIdx.x == 0) divsum[t] = (float)TT - s;
}

// AP[t,j]: i=j>>1, ang = t * 10000^(-i/512); even->sin, odd->cos
__global__ __launch_bounds__(256) void k_ap(float* __restrict__ AP) {
  int t = blockIdx.x;
  for (int j = threadIdx.x; j < TT; j += 256) {
    int i = j >> 1;
    float invf = __expf((float)i * -0.017988946039016016f); // -ln(1e4)/512
    float ang = (float)t * invf;
    AP[(size_t)t * TT + j] = (j & 1) ? cosf(ang) : sinf(ang);
  }
}

// ---- attention phase 1: per (h, row) stats M, logL, entropy_raw, dep ----
#define RT 64
#define ST 32
#define LDQ 132
__global__ __launch_bounds__(256) void k_phase1(
    const float* __restrict__ Qm, const float* __restrict__ Km,
    const float* __restrict__ AP, const float* __restrict__ Cm,
    const float* __restrict__ divsum,
    float* __restrict__ Mst, float* __restrict__ Lst,
    float* __restrict__ entraw, float* __restrict__ dep) {
  int h = blockIdx.y, r0 = blockIdx.x * RT;
  int tid = threadIdx.x, tx = tid & 15, ty = tid >> 4;
  __shared__ __align__(16) float Qs[RT][LDQ];
  __shared__ __align__(16) float Ks[ST][LDQ];
  for (int idx = tid; idx < RT * 32; idx += 256) {
    int r = idx >> 5, c4 = (idx & 31) << 2;
    *(float4*)&Qs[r][c4] = *(const float4*)&Qm[(size_t)(r0 + r) * 1024 + h * DH + c4];
  }
  float Mv[4], Lv[4], sae[4], dnum[4];
  #pragma unroll
  for (int i = 0; i < 4; i++) { Mv[i] = -1e30f; Lv[i] = 0.f; sae[i] = 0.f; dnum[i] = 0.f; }

  for (int s0 = 0; s0 < TT; s0 += ST) {
    __syncthreads();
    for (int idx = tid; idx < ST * 32; idx += 256) {
      int r = idx >> 5, c4 = (idx & 31) << 2;
      *(float4*)&Ks[r][c4] = *(const float4*)&Km[(size_t)(s0 + r) * 1024 + h * DH + c4];
    }
    __syncthreads();
    float e[4][2];
    #pragma unroll
    for (int i = 0; i < 4; i++) { e[i][0] = 0.f; e[i][1] = 0.f; }
    for (int kk = 0; kk < DH; kk += 4) {
      float4 ka = *(const float4*)&Ks[tx * 2 + 0][kk];
      float4 kb = *(const float4*)&Ks[tx * 2 + 1][kk];
      #pragma unroll
      for (int i = 0; i < 4; i++) {
        float4 q4 = *(const float4*)&Qs[ty * 4 + i][kk];
        e[i][0] += q4.x * ka.x + q4.y * ka.y + q4.z * ka.z + q4.w * ka.w;
        e[i][1] += q4.x * kb.x + q4.y * kb.y + q4.z * kb.z + q4.w * kb.w;
      }
    }
    #pragma unroll
    for (int i = 0; i < 4; i++) {
      int t = r0 + ty * 4 + i;
      e[i][0] += AP[(size_t)t * TT + s0 + tx * 2 + 0];
      e[i][1] += AP[(size_t)t * TT + s0 + tx * 2 + 1];
      float c0 = Cm[(size_t)t * TT + s0 + tx * 2 + 0];
      float c1 = Cm[(size_t)t * TT + s0 + tx * 2 + 1];
      float m2 = fmaxf(e[i][0], e[i][1]);
      #pragma unroll
      for (int m = 1; m < 16; m <<= 1) m2 = fmaxf(m2, __shfl_xor(m2, m, 16));
      float newM = fmaxf(Mv[i], m2);
      float p0 = __expf(e[i][0] - newM), p1 = __expf(e[i][1] - newM);
      float sp = p0 + p1;
      float se = p0 * e[i][0] + p1 * e[i][1];
      float sc = p0 * c0 + p1 * c1;
      #pragma unroll
      for (int m = 1; m < 16; m <<= 1) {
        sp += __shfl_xor(sp, m, 16);
        se += __shfl_xor(se, m, 16);
        sc += __shfl_xor(sc, m, 16);
      }
      float scale = __expf(Mv[i] - newM);
      Lv[i] = Lv[i] * scale + sp;
      sae[i] = sae[i] * scale + se;
      dnum[i] = dnum[i] * scale + sc;
      Mv[i] = newM;
    }
  }
  if (tx == 0) {
    #pragma unroll
    for (int i = 0; i < 4; i++) {
      int t = r0 + ty * 4 + i;
      float logL = logf(Lv[i]);
      Mst[h * TT + t] = Mv[i];
      Lst[h * TT + t] = logL;
      entraw[h * TT + t] = (Mv[i] + logL - sae[i] / Lv[i]) * (1.0f / LNT);
      dep[h * TT + t] = (1.f - dnum[i] / Lv[i]) / divsum[t];
    }
  }
}

// entropy normalize per head: ent = raw / max(sum|raw|, 1e-12)
__global__ __launch_bounds__(256) void k_entnorm(const float* __restrict__ entraw,
                                                 float* __restrict__ ent) {
  int h = blockIdx.x;
  float s = 0.f;
  for (int t = threadIdx.x; t < TT; t += 256) s += fabsf(entraw[h * TT + t]);
  s = blockReduceSum256(s);
  float inv = 1.f / fmaxf(s, 1e-12f);
  for (int t = threadIdx.x; t < TT; t += 256) ent[h * TT + t] = entraw[h * TT + t] * inv;
}

// ---- phase 2: att_win = exp(e-M-logL)*(1+dep[col]); y = att_win @ V;
//      head 7 also streams att_win to out2 ----
__global__ __launch_bounds__(256) void k_phase2(
    const float* __restrict__ Qm, const float* __restrict__ Km,
    const float* __restrict__ Vm, const float* __restrict__ AP,
    const float* __restrict__ Mst, const float* __restrict__ Lst,
    const float* __restrict__ dep,
    float* __restrict__ y, float* __restrict__ out2) {
  int h = blockIdx.y, r0 = blockIdx.x * RT;
  int tid = threadIdx.x, tx = tid & 15, ty = tid >> 4;
  __shared__ __align__(16) float Qs[RT][LDQ];
  __shared__ __align__(16) float Ks[ST][LDQ];
  __shared__ float wS[RT][ST + 1];
  for (int idx = tid; idx < RT * 32; idx += 256) {
    int r = idx >> 5, c4 = (idx & 31) << 2;
    *(float4*)&Qs[r][c4] = *(const float4*)&Qm[(size_t)(r0 + r) * 1024 + h * DH + c4];
  }
  float ml[4];
  #pragma unroll
  for (int i = 0; i < 4; i++)
    ml[i] = Mst[h * TT + r0 + ty * 4 + i] + Lst[h * TT + r0 + ty * 4 + i];

  int yr = tid & 63, e0 = (tid >> 6) * 32;
  float yacc[32];
  #pragma unroll
  for (int q = 0; q < 32; q++) yacc[q] = 0.f;

  for (int s0 = 0; s0 < TT; s0 += ST) {
    __syncthreads();
    for (int idx = tid; idx < ST * 32; idx += 256) {
      int r = idx >> 5, c4 = (idx & 31) << 2;
      *(float4*)&Ks[r][c4] = *(const float4*)&Km[(size_t)(s0 + r) * 1024 + h * DH + c4];
    }
    __syncthreads();
    float e[4][2];
    #pragma unroll
    for (int i = 0; i < 4; i++) { e[i][0] = 0.f; e[i][1] = 0.f; }
    for (int kk = 0; kk < DH; kk += 4) {
      float4 ka = *(const float4*)&Ks[tx * 2 + 0][kk];
      float4 kb = *(const float4*)&Ks[tx * 2 + 1][kk];
      #pragma unroll
      for (int i = 0; i < 4; i++) {
        float4 q4 = *(const float4*)&Qs[ty * 4 + i][kk];
        e[i][0] += q4.x * ka.x + q4.y * ka.y + q4.z * ka.z + q4.w * ka.w;
        e[i][1] += q4.x * kb.x + q4.y * kb.y + q4.z * kb.z + q4.w * kb.w;
      }
    }
    float d0 = dep[h * TT + s0 + tx * 2 + 0];
    float d1 = dep[h * TT + s0 + tx * 2 + 1];
    #pragma unroll
    for (int i = 0; i < 4; i++) {
      int t = r0 + ty * 4 + i;
      e[i][0] += AP[(size_t)t * TT + s0 + tx * 2 + 0];
      e[i][1] += AP[(size_t)t * TT + s0 + tx * 2 + 1];
      wS[ty * 4 + i][tx * 2 + 0] = __expf(e[i][0] - ml[i]) * (1.f + d0);
      wS[ty * 4 + i][tx * 2 + 1] = __expf(e[i][1] - ml[i]) * (1.f + d1);
    }
    __syncthreads();
    // y accumulation: thread -> (row yr, 32 cols at e0)
    for (int s = 0; s < ST; s++) {
      float wv = wS[yr][s];
      const float4* vp = (const float4*)&Vm[(size_t)(s0 + s) * 1024 + h * DH + e0];
      #pragma unroll
      for (int q = 0; q < 8; q++) {
        float4 v4 = vp[q];
        yacc[q * 4 + 0] += wv * v4.x;
        yacc[q * 4 + 1] += wv * v4.y;
        yacc[q * 4 + 2] += wv * v4.z;
        yacc[q * 4 + 3] += wv * v4.w;
      }
    }
    if (h == NH - 1) {
      for (int idx = tid; idx < RT * ST; idx += 256) {
        int r = idx >> 5, c = idx & 31;
        out2[(size_t)(r0 + r) * TT + s0 + c] = wS[r][c];
      }
    }
  }
  #pragma unroll
  for (int q = 0; q < 8; q++) {
    float4 v = make_float4(yacc[q * 4 + 0], yacc[q * 4 + 1], yacc[q * 4 + 2], yacc[q * 4 + 3]);
    *(float4*)&y[((size_t)h * TT + r0 + yr) * DH + e0 + q * 4] = v;
  }
}

// y_s = [y | entropy | dep] @ Wout2^T, placed into ycat[t, h*DH+o]
__global__ __launch_bounds__(256) void k_ys(const float* __restrict__ y,
                                            const float* __restrict__ ent,
                                            const float* __restrict__ dep,
                                            const float* __restrict__ W2,
                                            float* __restrict__ ycat) {
  int h = blockIdx.x, t0 = blockIdx.y * 2;
  int tid = threadIdx.x;
  __shared__ float yls[2][128];
  {
    int rr = tid >> 7, cc = tid & 127;
    yls[rr][cc] = y[((size_t)h * TT + t0 + rr) * DH + cc];
  }
  __syncthreads();
  int trow = tid >> 7, o = tid & 127;
  int t = t0 + trow;
  float et = ent[h * TT + t], dp = dep[h * TT + t];
  float s = 0.f;
  #pragma unroll 4
  for (int f = 0; f < DH; f++) s += yls[trow][f] * W2[o * 130 + f];
  s += et * W2[o * 130 + 128] + dp * W2[o * 130 + 129];
  ycat[(size_t)t * 1024 + h * DH + o] = s;
}

extern "C" void kernel_launch(void* const* d_in, const int* in_sizes, int n_in,
                              void* d_out, int out_size, void* d_ws, size_t ws_size,
                              hipStream_t stream) {
  const float* x  = (const float*)d_in[0];
  const float* Wq = (const float*)d_in[1];
  const float* Wk = (const float*)d_in[2];
  const float* Wv = (const float*)d_in[3];
  const float* W2 = (const float*)d_in[4];
  const float* Wo = (const float*)d_in[5];
  float* out  = (float*)d_out;                  // [T, 1024]
  float* out2 = out + (size_t)TT * DIN;         // att_win[-1]  [T, T]
  float* ws = (float*)d_ws;

  float* U      = ws + OFF_U;
  float* Cm     = ws + OFF_C;
  float* ybuf   = ws + OFF_Y;
  float* ycat   = ws + OFF_YCAT;
  float* Qm     = ws + OFF_Q;
  float* Km     = ws + OFF_K;
  float* Vm     = ws + OFF_V;
  float* AP     = ws + OFF_AP;
  float* divsum = ws + OFF_DIVSUM;
  float* Mst    = ws + OFF_MST;
  float* Lst    = ws + OFF_LST;
  float* entraw = ws + OFF_ENTRAW;
  float* ent    = ws + OFF_ENT;
  float* dep    = ws + OFF_DEP;

  k_rownorm<<<TT, 256, 0, stream>>>(x, U);
  k_gemm_nt<<<dim3(TT / BN, TT / BM), 256, 0, stream>>>(U, U, Cm, TT, TT, DIN);
  k_divsum<<<TT, 256, 0, stream>>>(Cm, divsum);
  k_gemm_nt<<<dim3(1024 / BN, TT / BM), 256, 0, stream>>>(x, Wq, Qm, TT, 1024, DIN);
  k_gemm_nt<<<dim3(1024 / BN, TT / BM), 256, 0, stream>>>(x, Wk, Km, TT, 1024, DIN);
  k_gemm_nt<<<dim3(1024 / BN, TT / BM), 256, 0, stream>>>(x, Wv, Vm, TT, 1024, DIN);
  k_ap<<<TT, 256, 0, stream>>>(AP);
  k_phase1<<<dim3(TT / RT, NH), 256, 0, stream>>>(Qm, Km, AP, Cm, divsum,
                                                  Mst, Lst, entraw, dep);
  k_entnorm<<<NH, 256, 0, stream>>>(entraw, ent);
  k_phase2<<<dim3(TT / RT, NH), 256, 0, stream>>>(Qm, Km, Vm, AP, Mst, Lst, dep,
                                                  ybuf, out2);
  k_ys<<<dim3(NH, TT / 2), 256, 0, stream>>>(ybuf, ent, dep, W2, ycat);
  k_gemm_nt<<<dim3(1024 / BN, TT / BM), 256, 0, stream>>>(ycat, Wo, out, TT, 1024, DIN);
}

// Round 2
// 984.037 us; speedup vs baseline: 1.9434x; 1.9434x over previous
//
#include <hip/hip_runtime.h>
#include <math.h>

#define TT  2048
#define NH  8
#define DH  128
#define LNT 7.6246189861593985f   // ln(2048)

typedef unsigned short ushort_t;
typedef __bf16 bf16x8 __attribute__((ext_vector_type(8)));
typedef float f32x4 __attribute__((ext_vector_type(4)));
typedef unsigned int uintx4 __attribute__((ext_vector_type(4)));

#define MFMA16(a, b, c) __builtin_amdgcn_mfma_f32_16x16x32_bf16(a, b, c, 0, 0, 0)

__device__ __forceinline__ bf16x8 ld8(const ushort_t* p) {
  uintx4 v = *(const uintx4*)p;
  return __builtin_bit_cast(bf16x8, v);
}
__device__ __forceinline__ ushort_t f2bf(float x) {
  unsigned u = __float_as_uint(x);
  return (ushort_t)((u + 0x7fffu + ((u >> 16) & 1u)) >> 16);
}
__device__ __forceinline__ float bf2f(ushort_t b) {
  return __uint_as_float(((unsigned)b) << 16);
}

// ---- workspace layout (float offsets). Proven ws >= 16,861,184 floats; we use 16,252,928.
enum : size_t {
  F_XH   = 0u,          // xh [1M]        -> y fp32 [0,2M) after QKV gemms
  F_XL   = 1048576u,    // xl [1M]
  F_UBF  = 2097152u,    // U bf16 [1M]    -> ycat bf16 after C gemm
  F_WQH  = 3145728u,    // [0.5M]         -> VT' bf16 [1M] after gemms
  F_WQL  = 3670016u,
  F_WKH  = 4194304u,    //                -> Wo bf16 [0.5M] after K gemm
  F_WKL  = 4718592u,    //                -> stats after gemms
  F_WVH  = 5242880u,
  F_QH   = 5767168u,    // [1M]
  F_QL   = 6815744u,
  F_KH   = 7864320u,
  F_KL   = 8912896u,
  F_VBF  = 9961472u,    // V bf16 [1M]
  F_C    = 11010048u,   // C fp32 [4M]
  F_APB  = 15204352u,   // AP bf16 [1M]
  // overlays
  F_Y    = 0u,          // y fp32 [H,T,DH] = 2M floats
  F_YCB  = 2097152u,    // ycat bf16 [T,1024]
  F_VT   = 3145728u,    // V'^T bf16 [H,DH,T]
  F_WOB  = 4194304u,    // Wout bf16 [1024,1024]
  F_DIVS = 4718592u,
  F_MST  = 4722688u,
  F_LST  = 4739072u,
  F_ENTR = 4755456u,
  F_ENT  = 4771840u,
  F_DEP  = 4788224u,
};

__device__ __forceinline__ float blockReduceSum256(float v) {
  __shared__ float sh[4];
  #pragma unroll
  for (int m = 1; m < 64; m <<= 1) v += __shfl_xor(v, m, 64);
  if ((threadIdx.x & 63) == 0) sh[threadIdx.x >> 6] = v;
  __syncthreads();
  float r = sh[0] + sh[1] + sh[2] + sh[3];
  __syncthreads();
  return r;
}

// U_bf[t,:] = bf16(x[t,:] / max(||x[t,:]||, 1e-12))
__global__ __launch_bounds__(256) void k_rownorm_bf(const float* __restrict__ x,
                                                    ushort_t* __restrict__ Ubf) {
  int t = blockIdx.x;
  const float* xr = x + (size_t)t * 1024;
  float ss = 0.f;
  for (int d = threadIdx.x; d < 1024; d += 256) { float v = xr[d]; ss += v * v; }
  ss = blockReduceSum256(ss);
  float inv = 1.f / fmaxf(sqrtf(ss), 1e-12f);
  for (int d = threadIdx.x; d < 1024; d += 256)
    Ubf[(size_t)t * 1024 + d] = f2bf(xr[d] * inv);
}

// float -> (hi, lo) bf16, 4 elems/thread
__global__ __launch_bounds__(256) void k_splitf(const float* __restrict__ s,
                                                ushort_t* __restrict__ hi,
                                                ushort_t* __restrict__ lo, int n4) {
  int i = blockIdx.x * 256 + threadIdx.x;
  if (i >= n4) return;
  float4 v = ((const float4*)s)[i];
  ushort_t h0 = f2bf(v.x), h1 = f2bf(v.y), h2 = f2bf(v.z), h3 = f2bf(v.w);
  uint2 hw, lw;
  hw.x = (unsigned)h0 | ((unsigned)h1 << 16);
  hw.y = (unsigned)h2 | ((unsigned)h3 << 16);
  lw.x = (unsigned)f2bf(v.x - bf2f(h0)) | ((unsigned)f2bf(v.y - bf2f(h1)) << 16);
  lw.y = (unsigned)f2bf(v.z - bf2f(h2)) | ((unsigned)f2bf(v.w - bf2f(h3)) << 16);
  ((uint2*)hi)[i] = hw;
  ((uint2*)lo)[i] = lw;
}

// float -> bf16
__global__ __launch_bounds__(256) void k_tobf(const float* __restrict__ s,
                                              ushort_t* __restrict__ d, int n4) {
  int i = blockIdx.x * 256 + threadIdx.x;
  if (i >= n4) return;
  float4 v = ((const float4*)s)[i];
  uint2 w;
  w.x = (unsigned)f2bf(v.x) | ((unsigned)f2bf(v.y) << 16);
  w.y = (unsigned)f2bf(v.z) | ((unsigned)f2bf(v.w) << 16);
  ((uint2*)d)[i] = w;
}

// Generic NT MFMA GEMM: D[M,N] = A[M,K] * B[N,K]^T, bf16 inputs, 64x64 tile/block.
// MODE 0: fp32 out; 1: split hi/lo bf16 out; 2: bf16 out.  BF3: A/B have lo parts.
template <int MODE, bool BF3>
__global__ __launch_bounds__(256) void k_gemm(
    const ushort_t* __restrict__ Ah, const ushort_t* __restrict__ Al,
    const ushort_t* __restrict__ Bh, const ushort_t* __restrict__ Bl,
    float* __restrict__ Df, ushort_t* __restrict__ Dh, ushort_t* __restrict__ Dl,
    int M, int N, int K) {
  int tid = threadIdx.x, lane = tid & 63, w = tid >> 6;
  int l15 = lane & 15, lg = lane >> 4;
  int m0 = blockIdx.y * 64 + w * 16, n0 = blockIdx.x * 64;
  f32x4 acc[4];
  #pragma unroll
  for (int ct = 0; ct < 4; ct++) acc[ct] = (f32x4)0.f;
  const ushort_t* ap = Ah + (size_t)(m0 + l15) * K + lg * 8;
  const ushort_t* alp = BF3 ? (Al + (size_t)(m0 + l15) * K + lg * 8) : nullptr;
  for (int k0 = 0; k0 < K; k0 += 32) {
    bf16x8 a = ld8(ap + k0);
    bf16x8 al;
    if (BF3) al = ld8(alp + k0);
    #pragma unroll
    for (int ct = 0; ct < 4; ct++) {
      size_t bo = (size_t)(n0 + ct * 16 + l15) * K + lg * 8 + k0;
      bf16x8 b = ld8(Bh + bo);
      acc[ct] = MFMA16(a, b, acc[ct]);
      if (BF3) {
        bf16x8 bl = ld8(Bl + bo);
        acc[ct] = MFMA16(al, b, acc[ct]);
        acc[ct] = MFMA16(a, bl, acc[ct]);
      }
    }
  }
  #pragma unroll
  for (int ct = 0; ct < 4; ct++) {
    #pragma unroll
    for (int r = 0; r < 4; r++) {
      size_t mm = m0 + lg * 4 + r, nn = n0 + ct * 16 + l15;
      float v = acc[ct][r];
      if (MODE == 0) Df[mm * N + nn] = v;
      if (MODE == 1) {
        ushort_t hh = f2bf(v);
        Dh[mm * N + nn] = hh;
        Dl[mm * N + nn] = f2bf(v - bf2f(hh));
      }
      if (MODE == 2) Dh[mm * N + nn] = f2bf(v);
    }
  }
}

// divsum[t] = T - sum_s C[t,s]
__global__ __launch_bounds__(256) void k_divsum(const float* __restrict__ C,
                                                float* __restrict__ divsum) {
  int t = blockIdx.x;
  float s = 0.f;
  for (int j = threadIdx.x; j < TT; j += 256) s += C[(size_t)t * TT + j];
  s = blockReduceSum256(s);
  if (threadIdx.x == 0) divsum[t] = (float)TT - s;
}

// AP bf16 table
__global__ __launch_bounds__(256) void k_apbf(ushort_t* __restrict__ APb) {
  int t = blockIdx.x;
  for (int j = threadIdx.x; j < TT; j += 256) {
    int i = j >> 1;
    float invf = __expf((float)i * -0.017988946039016016f); // -ln(1e4)/512
    float ang = (float)t * invf;
    APb[(size_t)t * TT + j] = f2bf((j & 1) ? cosf(ang) : sinf(ang));
  }
}

// ---- phase 1 (MFMA): per (h,row) stats M, logL, entropy_raw, dep ----
__global__ __launch_bounds__(256) void k_phase1m(
    const ushort_t* __restrict__ Qh, const ushort_t* __restrict__ Ql,
    const ushort_t* __restrict__ Kh, const ushort_t* __restrict__ Kl,
    const ushort_t* __restrict__ APb, const float* __restrict__ Cm,
    const float* __restrict__ divsum,
    float* __restrict__ Mst, float* __restrict__ Lst,
    float* __restrict__ entraw, float* __restrict__ dep) {
  int h = blockIdx.y;
  int tid = threadIdx.x, lane = tid & 63, w = tid >> 6;
  int l15 = lane & 15, lg = lane >> 4;
  int rowbase = blockIdx.x * 64 + w * 16;

  bf16x8 qh[4], ql[4];
  {
    const ushort_t* p1 = Qh + (size_t)(rowbase + l15) * 1024 + h * DH + lg * 8;
    const ushort_t* p2 = Ql + (size_t)(rowbase + l15) * 1024 + h * DH + lg * 8;
    #pragma unroll
    for (int kc = 0; kc < 4; kc++) { qh[kc] = ld8(p1 + kc * 32); ql[kc] = ld8(p2 + kc * 32); }
  }
  float Mv[4], Lv[4], sae[4], snc[4];
  #pragma unroll
  for (int r = 0; r < 4; r++) { Mv[r] = -1e30f; Lv[r] = 0.f; sae[r] = 0.f; snc[r] = 0.f; }

  for (int s0 = 0; s0 < TT; s0 += 64) {
    f32x4 acc[4];
    #pragma unroll
    for (int ct = 0; ct < 4; ct++) acc[ct] = (f32x4)0.f;
    #pragma unroll
    for (int ct = 0; ct < 4; ct++) {
      const ushort_t* kp1 = Kh + (size_t)(s0 + ct * 16 + l15) * 1024 + h * DH + lg * 8;
      const ushort_t* kp2 = Kl + (size_t)(s0 + ct * 16 + l15) * 1024 + h * DH + lg * 8;
      #pragma unroll
      for (int kc = 0; kc < 4; kc++) {
        bf16x8 bh = ld8(kp1 + kc * 32);
        bf16x8 bl = ld8(kp2 + kc * 32);
        acc[ct] = MFMA16(qh[kc], bh, acc[ct]);
        acc[ct] = MFMA16(ql[kc], bh, acc[ct]);
        acc[ct] = MFMA16(qh[kc], bl, acc[ct]);
      }
    }
    float e[4][4];
    #pragma unroll
    for (int r = 0; r < 4; r++)
      #pragma unroll
      for (int ct = 0; ct < 4; ct++)
        e[r][ct] = acc[ct][r] +
                   bf2f(APb[(size_t)(rowbase + lg * 4 + r) * TT + s0 + ct * 16 + l15]);
    #pragma unroll
    for (int r = 0; r < 4; r++) {
      int t = rowbase + lg * 4 + r;
      float m2 = fmaxf(fmaxf(e[r][0], e[r][1]), fmaxf(e[r][2], e[r][3]));
      #pragma unroll
      for (int m = 1; m < 16; m <<= 1) m2 = fmaxf(m2, __shfl_xor(m2, m, 64));
      float newM = fmaxf(Mv[r], m2);
      float sp = 0.f, se = 0.f, sc = 0.f;
      #pragma unroll
      for (int ct = 0; ct < 4; ct++) {
        float p = __expf(e[r][ct] - newM);
        float c = Cm[(size_t)t * TT + s0 + ct * 16 + l15];
        sp += p; se += p * e[r][ct]; sc += p * c;
      }
      #pragma unroll
      for (int m = 1; m < 16; m <<= 1) {
        sp += __shfl_xor(sp, m, 64);
        se += __shfl_xor(se, m, 64);
        sc += __shfl_xor(sc, m, 64);
      }
      float rs = __expf(Mv[r] - newM);
      Lv[r] = Lv[r] * rs + sp;
      sae[r] = sae[r] * rs + se;
      snc[r] = snc[r] * rs + sc;
      Mv[r] = newM;
    }
  }
  if (l15 == 0) {
    #pragma unroll
    for (int r = 0; r < 4; r++) {
      int t = rowbase + lg * 4 + r;
      float logL = __logf(Lv[r]);
      Mst[h * TT + t] = Mv[r];
      Lst[h * TT + t] = logL;
      entraw[h * TT + t] = (Mv[r] + logL - sae[r] / Lv[r]) * (1.0f / LNT);
      dep[h * TT + t] = (1.f - snc[r] / Lv[r]) / divsum[t];
    }
  }
}

// entropy normalize per head
__global__ __launch_bounds__(256) void k_entnorm(const float* __restrict__ entraw,
                                                 float* __restrict__ ent) {
  int h = blockIdx.x;
  float s = 0.f;
  for (int t = threadIdx.x; t < TT; t += 256) s += fabsf(entraw[h * TT + t]);
  s = blockReduceSum256(s);
  float inv = 1.f / fmaxf(s, 1e-12f);
  for (int t = threadIdx.x; t < TT; t += 256) ent[h * TT + t] = entraw[h * TT + t] * inv;
}

// V'^T[h][e][s] = bf16( V[s][h*DH+e] * (1+dep[h][s]) )
__global__ __launch_bounds__(256) void k_vprime(const ushort_t* __restrict__ Vbf,
                                                const float* __restrict__ dep,
                                                ushort_t* __restrict__ VT) {
  int h = blockIdx.y, s0 = blockIdx.x * 64;
  __shared__ float tile[64][130];
  int tid = threadIdx.x;
  for (int idx = tid; idx < 64 * 64; idx += 256) {
    int r = idx >> 6, c2 = (idx & 63) * 2;
    unsigned u = *(const unsigned*)&Vbf[(size_t)(s0 + r) * 1024 + h * DH + c2];
    tile[r][c2] = bf2f((ushort_t)(u & 0xffffu));
    tile[r][c2 + 1] = bf2f((ushort_t)(u >> 16));
  }
  __syncthreads();
  int e = tid >> 1, sh = (tid & 1) * 32;
  #pragma unroll
  for (int g = 0; g < 8; g++) {
    int sb = sh + g * 4;
    float v0 = tile[sb + 0][e] * (1.f + dep[h * TT + s0 + sb + 0]);
    float v1 = tile[sb + 1][e] * (1.f + dep[h * TT + s0 + sb + 1]);
    float v2 = tile[sb + 2][e] * (1.f + dep[h * TT + s0 + sb + 2]);
    float v3 = tile[sb + 3][e] * (1.f + dep[h * TT + s0 + sb + 3]);
    uint2 wv;
    wv.x = (unsigned)f2bf(v0) | ((unsigned)f2bf(v1) << 16);
    wv.y = (unsigned)f2bf(v2) | ((unsigned)f2bf(v3) << 16);
    *(uint2*)&VT[(size_t)(h * DH + e) * TT + s0 + sb] = wv;
  }
}

// ---- phase 2 (MFMA): y = att_win @ V'; head 7 writes att_win fp32 ----
__global__ __launch_bounds__(256) void k_phase2m(
    const ushort_t* __restrict__ Qh, const ushort_t* __restrict__ Ql,
    const ushort_t* __restrict__ Kh, const ushort_t* __restrict__ Kl,
    const ushort_t* __restrict__ APb, const ushort_t* __restrict__ VT,
    const float* __restrict__ Mst, const float* __restrict__ Lst,
    const float* __restrict__ dep,
    float* __restrict__ y, float* __restrict__ out2) {
  int h = blockIdx.y;
  int tid = threadIdx.x, lane = tid & 63, w = tid >> 6;
  int l15 = lane & 15, lg = lane >> 4;
  int rowbase = blockIdx.x * 64 + w * 16;
  bool last = (h == NH - 1);

  __shared__ __align__(16) ushort_t P[4][16][72];

  bf16x8 qh[4], ql[4];
  {
    const ushort_t* p1 = Qh + (size_t)(rowbase + l15) * 1024 + h * DH + lg * 8;
    const ushort_t* p2 = Ql + (size_t)(rowbase + l15) * 1024 + h * DH + lg * 8;
    #pragma unroll
    for (int kc = 0; kc < 4; kc++) { qh[kc] = ld8(p1 + kc * 32); ql[kc] = ld8(p2 + kc * 32); }
  }
  float ml[4];
  #pragma unroll
  for (int r = 0; r < 4; r++) {
    int t = rowbase + lg * 4 + r;
    ml[r] = Mst[h * TT + t] + Lst[h * TT + t];
  }
  f32x4 yacc[8];
  #pragma unroll
  for (int et = 0; et < 8; et++) yacc[et] = (f32x4)0.f;

  for (int s0 = 0; s0 < TT; s0 += 64) {
    f32x4 acc[4];
    #pragma unroll
    for (int ct = 0; ct < 4; ct++) acc[ct] = (f32x4)0.f;
    #pragma unroll
    for (int ct = 0; ct < 4; ct++) {
      const ushort_t* kp1 = Kh + (size_t)(s0 + ct * 16 + l15) * 1024 + h * DH + lg * 8;
      const ushort_t* kp2 = Kl + (size_t)(s0 + ct * 16 + l15) * 1024 + h * DH + lg * 8;
      #pragma unroll
      for (int kc = 0; kc < 4; kc++) {
        bf16x8 bh = ld8(kp1 + kc * 32);
        bf16x8 bl = ld8(kp2 + kc * 32);
        acc[ct] = MFMA16(qh[kc], bh, acc[ct]);
        acc[ct] = MFMA16(ql[kc], bh, acc[ct]);
        acc[ct] = MFMA16(qh[kc], bl, acc[ct]);
      }
    }
    float dv[4];
    if (last) {
      #pragma unroll
      for (int ct = 0; ct < 4; ct++) dv[ct] = dep[(NH - 1) * TT + s0 + ct * 16 + l15];
    }
    #pragma unroll
    for (int ct = 0; ct < 4; ct++) {
      #pragma unroll
      for (int r = 0; r < 4; r++) {
        int t = rowbase + lg * 4 + r;
        float e = acc[ct][r] + bf2f(APb[(size_t)t * TT + s0 + ct * 16 + l15]);
        float a = __expf(e - ml[r]);
        P[w][lg * 4 + r][ct * 16 + l15] = f2bf(a);
        if (last) out2[(size_t)t * TT + s0 + ct * 16 + l15] = a * (1.f + dv[ct]);
      }
    }
    asm volatile("" ::: "memory");   // order P writes before P reads (same-wave DS is in-order)
    #pragma unroll
    for (int c = 0; c < 2; c++) {
      bf16x8 ap = *(const bf16x8*)&P[w][l15][c * 32 + lg * 8];
      #pragma unroll
      for (int et = 0; et < 8; et++) {
        bf16x8 bv = ld8(VT + (size_t)(h * DH + et * 16 + l15) * TT + s0 + c * 32 + lg * 8);
        yacc[et] = MFMA16(ap, bv, yacc[et]);
      }
    }
    asm volatile("" ::: "memory");
  }
  #pragma unroll
  for (int et = 0; et < 8; et++)
    #pragma unroll
    for (int r = 0; r < 4; r++)
      y[((size_t)h * TT + rowbase + lg * 4 + r) * DH + et * 16 + l15] = yacc[et][r];
}

// y_s = [y | ent | dep] @ W2^T -> ycat bf16
__global__ __launch_bounds__(256) void k_ys(const float* __restrict__ y,
                                            const float* __restrict__ ent,
                                            const float* __restrict__ dep,
                                            const float* __restrict__ W2,
                                            ushort_t* __restrict__ ycatb) {
  int h = blockIdx.x, t0 = blockIdx.y * 2;
  int tid = threadIdx.x;
  __shared__ float yls[2][128];
  {
    int rr = tid >> 7, cc = tid & 127;
    yls[rr][cc] = y[((size_t)h * TT + t0 + rr) * DH + cc];
  }
  __syncthreads();
  int trow = tid >> 7, o = tid & 127;
  int t = t0 + trow;
  float et = ent[h * TT + t], dp = dep[h * TT + t];
  float s = 0.f;
  #pragma unroll 4
  for (int f = 0; f < DH; f++) s += yls[trow][f] * W2[o * 130 + f];
  s += et * W2[o * 130 + 128] + dp * W2[o * 130 + 129];
  ycatb[(size_t)t * 1024 + h * DH + o] = f2bf(s);
}

extern "C" void kernel_launch(void* const* d_in, const int* in_sizes, int n_in,
                              void* d_out, int out_size, void* d_ws, size_t ws_size,
                              hipStream_t stream) {
  const float* x  = (const float*)d_in[0];
  const float* Wq = (const float*)d_in[1];
  const float* Wk = (const float*)d_in[2];
  const float* Wv = (const float*)d_in[3];
  const float* W2 = (const float*)d_in[4];
  const float* Wo = (const float*)d_in[5];
  float* out  = (float*)d_out;                  // [T,1024]
  float* out2 = out + (size_t)TT * 1024;        // att_win[-1] [T,T]
  float* ws = (float*)d_ws;

  ushort_t* xh   = (ushort_t*)(ws + F_XH);
  ushort_t* xl   = (ushort_t*)(ws + F_XL);
  ushort_t* Ubf  = (ushort_t*)(ws + F_UBF);
  ushort_t* Wqh  = (ushort_t*)(ws + F_WQH);
  ushort_t* Wql  = (ushort_t*)(ws + F_WQL);
  ushort_t* Wkh  = (ushort_t*)(ws + F_WKH);
  ushort_t* Wkl  = (ushort_t*)(ws + F_WKL);
  ushort_t* Wvh  = (ushort_t*)(ws + F_WVH);
  ushort_t* QhB  = (ushort_t*)(ws + F_QH);
  ushort_t* QlB  = (ushort_t*)(ws + F_QL);
  ushort_t* KhB  = (ushort_t*)(ws + F_KH);
  ushort_t* KlB  = (ushort_t*)(ws + F_KL);
  ushort_t* Vbf  = (ushort_t*)(ws + F_VBF);
  float*    Cm   = ws + F_C;
  ushort_t* APb  = (ushort_t*)(ws + F_APB);
  float*    ybuf = ws + F_Y;
  ushort_t* ycb  = (ushort_t*)(ws + F_YCB);
  ushort_t* VT   = (ushort_t*)(ws + F_VT);
  ushort_t* Wob  = (ushort_t*)(ws + F_WOB);
  float* divsum = ws + F_DIVS;
  float* Mst    = ws + F_MST;
  float* Lst    = ws + F_LST;
  float* entraw = ws + F_ENTR;
  float* ent    = ws + F_ENT;
  float* dep    = ws + F_DEP;

  k_rownorm_bf<<<TT, 256, 0, stream>>>(x, Ubf);
  k_splitf<<<2048, 256, 0, stream>>>(x, xh, xl, 524288);
  k_splitf<<<1024, 256, 0, stream>>>(Wq, Wqh, Wql, 262144);
  k_splitf<<<1024, 256, 0, stream>>>(Wk, Wkh, Wkl, 262144);
  k_tobf<<<1024, 256, 0, stream>>>(Wv, Wvh, 262144);

  k_gemm<0, false><<<dim3(32, 32), 256, 0, stream>>>(Ubf, nullptr, Ubf, nullptr,
                                                     Cm, nullptr, nullptr, TT, TT, 1024);
  k_gemm<1, true><<<dim3(16, 32), 256, 0, stream>>>(xh, xl, Wqh, Wql,
                                                    nullptr, QhB, QlB, TT, 1024, 1024);
  k_gemm<1, true><<<dim3(16, 32), 256, 0, stream>>>(xh, xl, Wkh, Wkl,
                                                    nullptr, KhB, KlB, TT, 1024, 1024);
  k_gemm<2, false><<<dim3(16, 32), 256, 0, stream>>>(xh, nullptr, Wvh, nullptr,
                                                     nullptr, Vbf, nullptr, TT, 1024, 1024);
  k_tobf<<<1024, 256, 0, stream>>>(Wo, Wob, 262144);   // after K gemm (region overlay)

  k_divsum<<<TT, 256, 0, stream>>>(Cm, divsum);        // after gemms (stats overlay Wkl)
  k_apbf<<<TT, 256, 0, stream>>>(APb);

  k_phase1m<<<dim3(32, NH), 256, 0, stream>>>(QhB, QlB, KhB, KlB, APb, Cm, divsum,
                                              Mst, Lst, entraw, dep);
  k_entnorm<<<NH, 256, 0, stream>>>(entraw, ent);
  k_vprime<<<dim3(32, NH), 256, 0, stream>>>(Vbf, dep, VT);
  k_phase2m<<<dim3(32, NH), 256, 0, stream>>>(QhB, QlB, KhB, KlB, APb, VT,
                                              Mst, Lst, dep, ybuf, out2);
  k_ys<<<dim3(NH, TT / 2), 256, 0, stream>>>(ybuf, ent, dep, W2, ycb);
  k_gemm<0, false><<<dim3(16, 32), 256, 0, stream>>>(ycb, nullptr, Wob, nullptr,
                                                     out, nullptr, nullptr, TT, 1024, 1024);
}

// Round 3
// 776.266 us; speedup vs baseline: 2.4635x; 1.2677x over previous
//
#include <hip/hip_runtime.h>
#include <math.h>

#define TT  2048
#define NH  8
#define DH  128
#define LNT 7.6246189861593985f   // ln(2048)

typedef unsigned short ushort_t;
typedef __bf16 bf16x8 __attribute__((ext_vector_type(8)));
typedef float f32x4 __attribute__((ext_vector_type(4)));
typedef unsigned int uintx4 __attribute__((ext_vector_type(4)));

#define MFMA16(a, b, c) __builtin_amdgcn_mfma_f32_16x16x32_bf16(a, b, c, 0, 0, 0)

__device__ __forceinline__ bf16x8 ld8(const ushort_t* p) {
  uintx4 v = *(const uintx4*)p;
  return __builtin_bit_cast(bf16x8, v);
}
__device__ __forceinline__ ushort_t f2bf(float x) {
  unsigned u = __float_as_uint(x);
  return (ushort_t)((u + 0x7fffu + ((u >> 16) & 1u)) >> 16);
}
__device__ __forceinline__ float bf2f(ushort_t b) {
  return __uint_as_float(((unsigned)b) << 16);
}

// ---- workspace layout (float offsets). Max footprint 17,301,504 floats (69.2MB),
//      identical to the round-2 proven-safe bound.
enum : size_t {
  F_XH   = 0u,          // xh [1M]     -> ypart0 fp32 [2M] during phase2
  F_XL   = 1048576u,
  F_UBF  = 2097152u,    // U bf16 [1M] -> ycat bf16 after C gemm
  F_WQH  = 3145728u,    //             -> VT' bf16 [1M] after gemms
  F_WQL  = 3670016u,
  F_WKH  = 4194304u,    //             -> Wo bf16 [0.5M] after K gemm
  F_WKL  = 4718592u,    //             -> stats after gemms
  F_WVH  = 5242880u,
  F_QH   = 5767168u,
  F_QL   = 6815744u,
  F_KH   = 7864320u,
  F_KL   = 8912896u,
  F_VBF  = 9961472u,    // V bf16 [1M]
  F_C    = 11010048u,   // C fp32 [4M] -> ypart1/ypart2 during phase2
  F_APB  = 15204352u,   // AP bf16 [2M floats]
  // overlays
  F_Y    = 0u,          // ypart0 / final y accumulate target
  F_YCB  = 2097152u,
  F_VT   = 3145728u,
  F_WOB  = 4194304u,
  F_DIVS = 4718592u,
  F_MST  = 4722688u,
  F_LST  = 4739072u,
  F_ENTR = 4755456u,
  F_ENT  = 4771840u,
  F_DEP  = 4788224u,
  F_MP   = 4804608u,    // partial stats [4][NH*TT] x4 arrays = 262144 floats
  F_LP   = 4870144u,
  F_SAP  = 4935680u,
  F_SCP  = 5001216u,    // ends 5066752 < 5242880 (Wv dead by then)
  F_YP1  = 11010048u,   // phase2 partial y chunk1 [2M]
  F_YP2  = 13107200u,   // chunk2 [2M]
};

__device__ __forceinline__ float blockReduceSum256(float v) {
  __shared__ float sh[4];
  #pragma unroll
  for (int m = 1; m < 64; m <<= 1) v += __shfl_xor(v, m, 64);
  if ((threadIdx.x & 63) == 0) sh[threadIdx.x >> 6] = v;
  __syncthreads();
  float r = sh[0] + sh[1] + sh[2] + sh[3];
  __syncthreads();
  return r;
}

__global__ __launch_bounds__(256) void k_rownorm_bf(const float* __restrict__ x,
                                                    ushort_t* __restrict__ Ubf) {
  int t = blockIdx.x;
  const float* xr = x + (size_t)t * 1024;
  float ss = 0.f;
  for (int d = threadIdx.x; d < 1024; d += 256) { float v = xr[d]; ss += v * v; }
  ss = blockReduceSum256(ss);
  float inv = 1.f / fmaxf(sqrtf(ss), 1e-12f);
  for (int d = threadIdx.x; d < 1024; d += 256)
    Ubf[(size_t)t * 1024 + d] = f2bf(xr[d] * inv);
}

__global__ __launch_bounds__(256) void k_splitf(const float* __restrict__ s,
                                                ushort_t* __restrict__ hi,
                                                ushort_t* __restrict__ lo, int n4) {
  int i = blockIdx.x * 256 + threadIdx.x;
  if (i >= n4) return;
  float4 v = ((const float4*)s)[i];
  ushort_t h0 = f2bf(v.x), h1 = f2bf(v.y), h2 = f2bf(v.z), h3 = f2bf(v.w);
  uint2 hw, lw;
  hw.x = (unsigned)h0 | ((unsigned)h1 << 16);
  hw.y = (unsigned)h2 | ((unsigned)h3 << 16);
  lw.x = (unsigned)f2bf(v.x - bf2f(h0)) | ((unsigned)f2bf(v.y - bf2f(h1)) << 16);
  lw.y = (unsigned)f2bf(v.z - bf2f(h2)) | ((unsigned)f2bf(v.w - bf2f(h3)) << 16);
  ((uint2*)hi)[i] = hw;
  ((uint2*)lo)[i] = lw;
}

__global__ __launch_bounds__(256) void k_tobf(const float* __restrict__ s,
                                              ushort_t* __restrict__ d, int n4) {
  int i = blockIdx.x * 256 + threadIdx.x;
  if (i >= n4) return;
  float4 v = ((const float4*)s)[i];
  uint2 w;
  w.x = (unsigned)f2bf(v.x) | ((unsigned)f2bf(v.y) << 16);
  w.y = (unsigned)f2bf(v.z) | ((unsigned)f2bf(v.w) << 16);
  ((uint2*)d)[i] = w;
}

// NT MFMA GEMM: D[M,N] = A[M,K]*B[N,K]^T, 64x64 tile/block.
template <int MODE, bool BF3>   // MODE 0: f32 out; 1: hi/lo bf16; 2: bf16
__global__ __launch_bounds__(256) void k_gemm(
    const ushort_t* __restrict__ Ah, const ushort_t* __restrict__ Al,
    const ushort_t* __restrict__ Bh, const ushort_t* __restrict__ Bl,
    float* __restrict__ Df, ushort_t* __restrict__ Dh, ushort_t* __restrict__ Dl,
    int M, int N, int K) {
  int tid = threadIdx.x, lane = tid & 63, w = tid >> 6;
  int l15 = lane & 15, lg = lane >> 4;
  int m0 = blockIdx.y * 64 + w * 16, n0 = blockIdx.x * 64;
  f32x4 acc[4];
  #pragma unroll
  for (int ct = 0; ct < 4; ct++) acc[ct] = (f32x4)0.f;
  const ushort_t* ap = Ah + (size_t)(m0 + l15) * K + lg * 8;
  const ushort_t* alp = BF3 ? (Al + (size_t)(m0 + l15) * K + lg * 8) : nullptr;
  for (int k0 = 0; k0 < K; k0 += 32) {
    bf16x8 a = ld8(ap + k0);
    bf16x8 al;
    if (BF3) al = ld8(alp + k0);
    #pragma unroll
    for (int ct = 0; ct < 4; ct++) {
      size_t bo = (size_t)(n0 + ct * 16 + l15) * K + lg * 8 + k0;
      bf16x8 b = ld8(Bh + bo);
      acc[ct] = MFMA16(a, b, acc[ct]);
      if (BF3) {
        bf16x8 bl = ld8(Bl + bo);
        acc[ct] = MFMA16(al, b, acc[ct]);
        acc[ct] = MFMA16(a, bl, acc[ct]);
      }
    }
  }
  #pragma unroll
  for (int ct = 0; ct < 4; ct++) {
    #pragma unroll
    for (int r = 0; r < 4; r++) {
      size_t mm = m0 + lg * 4 + r, nn = n0 + ct * 16 + l15;
      float v = acc[ct][r];
      if (MODE == 0) Df[mm * N + nn] = v;
      if (MODE == 1) {
        ushort_t hh = f2bf(v);
        Dh[mm * N + nn] = hh;
        Dl[mm * N + nn] = f2bf(v - bf2f(hh));
      }
      if (MODE == 2) Dh[mm * N + nn] = f2bf(v);
    }
  }
}

__global__ __launch_bounds__(256) void k_divsum(const float* __restrict__ C,
                                                float* __restrict__ divsum) {
  int t = blockIdx.x;
  float s = 0.f;
  for (int j = threadIdx.x; j < TT; j += 256) s += C[(size_t)t * TT + j];
  s = blockReduceSum256(s);
  if (threadIdx.x == 0) divsum[t] = (float)TT - s;
}

__global__ __launch_bounds__(256) void k_apbf(ushort_t* __restrict__ APb) {
  int t = blockIdx.x;
  for (int j = threadIdx.x; j < TT; j += 256) {
    int i = j >> 1;
    float invf = __expf((float)i * -0.017988946039016016f); // -ln(1e4)/512
    float ang = (float)t * invf;
    APb[(size_t)t * TT + j] = f2bf((j & 1) ? cosf(ang) : sinf(ang));
  }
}

// ---- phase 1: per-lane online stats, s-chunked (4 chunks of 512), no inner shuffles ----
__global__ __launch_bounds__(256) void k_phase1m(
    const ushort_t* __restrict__ Qh, const ushort_t* __restrict__ Ql,
    const ushort_t* __restrict__ Kh, const ushort_t* __restrict__ Kl,
    const ushort_t* __restrict__ APb, const float* __restrict__ Cm,
    float* __restrict__ Mp, float* __restrict__ Lp,
    float* __restrict__ sap, float* __restrict__ scp) {
  int h = blockIdx.y, c = blockIdx.z;
  int tid = threadIdx.x, lane = tid & 63, w = tid >> 6;
  int l15 = lane & 15, lg = lane >> 4;
  int rowbase = blockIdx.x * 64 + w * 16;
  int s_begin = c * 512, s_end = s_begin + 512;

  bf16x8 qh[4], ql[4];
  {
    const ushort_t* p1 = Qh + (size_t)(rowbase + l15) * 1024 + h * DH + lg * 8;
    const ushort_t* p2 = Ql + (size_t)(rowbase + l15) * 1024 + h * DH + lg * 8;
    #pragma unroll
    for (int kc = 0; kc < 4; kc++) { qh[kc] = ld8(p1 + kc * 32); ql[kc] = ld8(p2 + kc * 32); }
  }
  float Mv[4], Lv[4], sae[4], snc[4];
  #pragma unroll
  for (int r = 0; r < 4; r++) { Mv[r] = -1e30f; Lv[r] = 0.f; sae[r] = 0.f; snc[r] = 0.f; }

  for (int s0 = s_begin; s0 < s_end; s0 += 64) {
    f32x4 acc[4];
    #pragma unroll
    for (int ct = 0; ct < 4; ct++) acc[ct] = (f32x4)0.f;
    #pragma unroll
    for (int ct = 0; ct < 4; ct++) {
      const ushort_t* kp1 = Kh + (size_t)(s0 + ct * 16 + l15) * 1024 + h * DH + lg * 8;
      const ushort_t* kp2 = Kl + (size_t)(s0 + ct * 16 + l15) * 1024 + h * DH + lg * 8;
      #pragma unroll
      for (int kc = 0; kc < 4; kc++) {
        bf16x8 bh = ld8(kp1 + kc * 32);
        bf16x8 bl = ld8(kp2 + kc * 32);
        acc[ct] = MFMA16(qh[kc], bh, acc[ct]);
        acc[ct] = MFMA16(ql[kc], bh, acc[ct]);
        acc[ct] = MFMA16(qh[kc], bl, acc[ct]);
      }
    }
    #pragma unroll
    for (int r = 0; r < 4; r++) {
      int t = rowbase + lg * 4 + r;
      float e0 = acc[0][r] + bf2f(APb[(size_t)t * TT + s0 + 0 * 16 + l15]);
      float e1 = acc[1][r] + bf2f(APb[(size_t)t * TT + s0 + 1 * 16 + l15]);
      float e2 = acc[2][r] + bf2f(APb[(size_t)t * TT + s0 + 2 * 16 + l15]);
      float e3 = acc[3][r] + bf2f(APb[(size_t)t * TT + s0 + 3 * 16 + l15]);
      float c0 = Cm[(size_t)t * TT + s0 + 0 * 16 + l15];
      float c1 = Cm[(size_t)t * TT + s0 + 1 * 16 + l15];
      float c2 = Cm[(size_t)t * TT + s0 + 2 * 16 + l15];
      float c3 = Cm[(size_t)t * TT + s0 + 3 * 16 + l15];
      float m2 = fmaxf(fmaxf(e0, e1), fmaxf(e2, e3));
      float newM = fmaxf(Mv[r], m2);
      float rs = __expf(Mv[r] - newM);
      float p0 = __expf(e0 - newM), p1 = __expf(e1 - newM);
      float p2 = __expf(e2 - newM), p3 = __expf(e3 - newM);
      Lv[r]  = Lv[r]  * rs + (p0 + p1) + (p2 + p3);
      sae[r] = sae[r] * rs + (p0 * e0 + p1 * e1) + (p2 * e2 + p3 * e3);
      snc[r] = snc[r] * rs + (p0 * c0 + p1 * c1) + (p2 * c2 + p3 * c3);
      Mv[r] = newM;
    }
  }
  // merge across the 16 lanes of each row group (once per kernel)
  #pragma unroll
  for (int r = 0; r < 4; r++) {
    #pragma unroll
    for (int m = 1; m < 16; m <<= 1) {
      float Mo = __shfl_xor(Mv[r], m, 64);
      float Lo = __shfl_xor(Lv[r], m, 64);
      float so = __shfl_xor(sae[r], m, 64);
      float co = __shfl_xor(snc[r], m, 64);
      float nM = fmaxf(Mv[r], Mo);
      float s1 = __expf(Mv[r] - nM), s2 = __expf(Mo - nM);
      Lv[r]  = Lv[r]  * s1 + Lo * s2;
      sae[r] = sae[r] * s1 + so * s2;
      snc[r] = snc[r] * s1 + co * s2;
      Mv[r] = nM;
    }
  }
  if (l15 == 0) {
    #pragma unroll
    for (int r = 0; r < 4; r++) {
      int t = rowbase + lg * 4 + r;
      size_t idx = (size_t)c * (NH * TT) + h * TT + t;
      Mp[idx] = Mv[r]; Lp[idx] = Lv[r]; sap[idx] = sae[r]; scp[idx] = snc[r];
    }
  }
}

// merge 4 s-chunks -> final stats
__global__ __launch_bounds__(256) void k_combine(
    const float* __restrict__ Mp, const float* __restrict__ Lp,
    const float* __restrict__ sap, const float* __restrict__ scp,
    const float* __restrict__ divsum,
    float* __restrict__ Mst, float* __restrict__ Lst,
    float* __restrict__ entraw, float* __restrict__ dep) {
  int i = blockIdx.x * 256 + threadIdx.x;
  if (i >= NH * TT) return;
  float M = -1e30f, L = 0.f, sa = 0.f, sc = 0.f;
  #pragma unroll
  for (int c = 0; c < 4; c++) {
    size_t idx = (size_t)c * (NH * TT) + i;
    float Mc = Mp[idx], Lc = Lp[idx], sac = sap[idx], scc = scp[idx];
    float nM = fmaxf(M, Mc);
    float s1 = __expf(M - nM), s2 = __expf(Mc - nM);
    L = L * s1 + Lc * s2;
    sa = sa * s1 + sac * s2;
    sc = sc * s1 + scc * s2;
    M = nM;
  }
  float logL = __logf(L);
  Mst[i] = M; Lst[i] = logL;
  entraw[i] = (M + logL - sa / L) * (1.0f / LNT);
  int t = i & (TT - 1);
  dep[i] = (1.f - sc / L) / divsum[t];
}

__global__ __launch_bounds__(256) void k_entnorm(const float* __restrict__ entraw,
                                                 float* __restrict__ ent) {
  int h = blockIdx.x;
  float s = 0.f;
  for (int t = threadIdx.x; t < TT; t += 256) s += fabsf(entraw[h * TT + t]);
  s = blockReduceSum256(s);
  float inv = 1.f / fmaxf(s, 1e-12f);
  for (int t = threadIdx.x; t < TT; t += 256) ent[h * TT + t] = entraw[h * TT + t] * inv;
}

// V'^T[h][e][s] = bf16( V[s][h*DH+e] * (1+dep[h][s]) )
__global__ __launch_bounds__(256) void k_vprime(const ushort_t* __restrict__ Vbf,
                                                const float* __restrict__ dep,
                                                ushort_t* __restrict__ VT) {
  int h = blockIdx.y, s0 = blockIdx.x * 64;
  __shared__ float tile[64][130];
  int tid = threadIdx.x;
  for (int idx = tid; idx < 64 * 64; idx += 256) {
    int r = idx >> 6, c2 = (idx & 63) * 2;
    unsigned u = *(const unsigned*)&Vbf[(size_t)(s0 + r) * 1024 + h * DH + c2];
    tile[r][c2] = bf2f((ushort_t)(u & 0xffffu));
    tile[r][c2 + 1] = bf2f((ushort_t)(u >> 16));
  }
  __syncthreads();
  int e = tid >> 1, sh = (tid & 1) * 32;
  #pragma unroll
  for (int g = 0; g < 8; g++) {
    int sb = sh + g * 4;
    float v0 = tile[sb + 0][e] * (1.f + dep[h * TT + s0 + sb + 0]);
    float v1 = tile[sb + 1][e] * (1.f + dep[h * TT + s0 + sb + 1]);
    float v2 = tile[sb + 2][e] * (1.f + dep[h * TT + s0 + sb + 2]);
    float v3 = tile[sb + 3][e] * (1.f + dep[h * TT + s0 + sb + 3]);
    uint2 wv;
    wv.x = (unsigned)f2bf(v0) | ((unsigned)f2bf(v1) << 16);
    wv.y = (unsigned)f2bf(v2) | ((unsigned)f2bf(v3) << 16);
    *(uint2*)&VT[(size_t)(h * DH + e) * TT + s0 + sb] = wv;
  }
}

// ---- phase 2: s-chunked (3 chunks: 640/704/704), private partial-y buffers ----
__global__ __launch_bounds__(256) void k_phase2m(
    const ushort_t* __restrict__ Qh, const ushort_t* __restrict__ Ql,
    const ushort_t* __restrict__ Kh, const ushort_t* __restrict__ Kl,
    const ushort_t* __restrict__ APb, const ushort_t* __restrict__ VT,
    const float* __restrict__ Mst, const float* __restrict__ Lst,
    const float* __restrict__ dep,
    float* __restrict__ yp0, float* __restrict__ yp1, float* __restrict__ yp2,
    float* __restrict__ out2) {
  int h = blockIdx.y, z = blockIdx.z;
  int tid = threadIdx.x, lane = tid & 63, w = tid >> 6;
  int l15 = lane & 15, lg = lane >> 4;
  int rowbase = blockIdx.x * 64 + w * 16;
  bool last = (h == NH - 1);
  int s_begin = (z == 0) ? 0 : (z == 1) ? 640 : 1344;
  int s_end   = (z == 0) ? 640 : (z == 1) ? 1344 : 2048;
  float* yp = (z == 0) ? yp0 : (z == 1) ? yp1 : yp2;

  __shared__ __align__(16) ushort_t P[4][16][72];

  bf16x8 qh[4], ql[4];
  {
    const ushort_t* p1 = Qh + (size_t)(rowbase + l15) * 1024 + h * DH + lg * 8;
    const ushort_t* p2 = Ql + (size_t)(rowbase + l15) * 1024 + h * DH + lg * 8;
    #pragma unroll
    for (int kc = 0; kc < 4; kc++) { qh[kc] = ld8(p1 + kc * 32); ql[kc] = ld8(p2 + kc * 32); }
  }
  float ml[4];
  #pragma unroll
  for (int r = 0; r < 4; r++) {
    int t = rowbase + lg * 4 + r;
    ml[r] = Mst[h * TT + t] + Lst[h * TT + t];
  }
  f32x4 yacc[8];
  #pragma unroll
  for (int et = 0; et < 8; et++) yacc[et] = (f32x4)0.f;

  for (int s0 = s_begin; s0 < s_end; s0 += 64) {
    f32x4 acc[4];
    #pragma unroll
    for (int ct = 0; ct < 4; ct++) acc[ct] = (f32x4)0.f;
    #pragma unroll
    for (int ct = 0; ct < 4; ct++) {
      const ushort_t* kp1 = Kh + (size_t)(s0 + ct * 16 + l15) * 1024 + h * DH + lg * 8;
      const ushort_t* kp2 = Kl + (size_t)(s0 + ct * 16 + l15) * 1024 + h * DH + lg * 8;
      #pragma unroll
      for (int kc = 0; kc < 4; kc++) {
        bf16x8 bh = ld8(kp1 + kc * 32);
        bf16x8 bl = ld8(kp2 + kc * 32);
        acc[ct] = MFMA16(qh[kc], bh, acc[ct]);
        acc[ct] = MFMA16(ql[kc], bh, acc[ct]);
        acc[ct] = MFMA16(qh[kc], bl, acc[ct]);
      }
    }
    float dv[4];
    if (last) {
      #pragma unroll
      for (int ct = 0; ct < 4; ct++) dv[ct] = dep[(NH - 1) * TT + s0 + ct * 16 + l15];
    }
    #pragma unroll
    for (int ct = 0; ct < 4; ct++) {
      #pragma unroll
      for (int r = 0; r < 4; r++) {
        int t = rowbase + lg * 4 + r;
        float e = acc[ct][r] + bf2f(APb[(size_t)t * TT + s0 + ct * 16 + l15]);
        float a = __expf(e - ml[r]);
        P[w][lg * 4 + r][ct * 16 + l15] = f2bf(a);
        if (last) out2[(size_t)t * TT + s0 + ct * 16 + l15] = a * (1.f + dv[ct]);
      }
    }
    asm volatile("" ::: "memory");   // order P writes before P reads (same-wave DS is in-order)
    #pragma unroll
    for (int c = 0; c < 2; c++) {
      bf16x8 ap = *(const bf16x8*)&P[w][l15][c * 32 + lg * 8];
      #pragma unroll
      for (int et = 0; et < 8; et++) {
        bf16x8 bv = ld8(VT + (size_t)(h * DH + et * 16 + l15) * TT + s0 + c * 32 + lg * 8);
        yacc[et] = MFMA16(ap, bv, yacc[et]);
      }
    }
    asm volatile("" ::: "memory");
  }
  #pragma unroll
  for (int et = 0; et < 8; et++)
    #pragma unroll
    for (int r = 0; r < 4; r++)
      yp[((size_t)h * TT + rowbase + lg * 4 + r) * DH + et * 16 + l15] = yacc[et][r];
}

// y_s = [sum(ypart) | ent | dep] @ W2^T -> ycat bf16
__global__ __launch_bounds__(256) void k_ys(const float* __restrict__ yp0,
                                            const float* __restrict__ yp1,
                                            const float* __restrict__ yp2,
                                            const float* __restrict__ ent,
                                            const float* __restrict__ dep,
                                            const float* __restrict__ W2,
                                            ushort_t* __restrict__ ycatb) {
  int h = blockIdx.x, t0 = blockIdx.y * 2;
  int tid = threadIdx.x;
  __shared__ float yls[2][128];
  {
    int rr = tid >> 7, cc = tid & 127;
    size_t idx = ((size_t)h * TT + t0 + rr) * DH + cc;
    yls[rr][cc] = yp0[idx] + yp1[idx] + yp2[idx];
  }
  __syncthreads();
  int trow = tid >> 7, o = tid & 127;
  int t = t0 + trow;
  float et = ent[h * TT + t], dp = dep[h * TT + t];
  float s = 0.f;
  #pragma unroll 4
  for (int f = 0; f < DH; f++) s += yls[trow][f] * W2[o * 130 + f];
  s += et * W2[o * 130 + 128] + dp * W2[o * 130 + 129];
  ycatb[(size_t)t * 1024 + h * DH + o] = f2bf(s);
}

extern "C" void kernel_launch(void* const* d_in, const int* in_sizes, int n_in,
                              void* d_out, int out_size, void* d_ws, size_t ws_size,
                              hipStream_t stream) {
  const float* x  = (const float*)d_in[0];
  const float* Wq = (const float*)d_in[1];
  const float* Wk = (const float*)d_in[2];
  const float* Wv = (const float*)d_in[3];
  const float* W2 = (const float*)d_in[4];
  const float* Wo = (const float*)d_in[5];
  float* out  = (float*)d_out;                  // [T,1024]
  float* out2 = out + (size_t)TT * 1024;        // att_win[-1] [T,T]
  float* ws = (float*)d_ws;

  ushort_t* xh   = (ushort_t*)(ws + F_XH);
  ushort_t* xl   = (ushort_t*)(ws + F_XL);
  ushort_t* Ubf  = (ushort_t*)(ws + F_UBF);
  ushort_t* Wqh  = (ushort_t*)(ws + F_WQH);
  ushort_t* Wql  = (ushort_t*)(ws + F_WQL);
  ushort_t* Wkh  = (ushort_t*)(ws + F_WKH);
  ushort_t* Wkl  = (ushort_t*)(ws + F_WKL);
  ushort_t* Wvh  = (ushort_t*)(ws + F_WVH);
  ushort_t* QhB  = (ushort_t*)(ws + F_QH);
  ushort_t* QlB  = (ushort_t*)(ws + F_QL);
  ushort_t* KhB  = (ushort_t*)(ws + F_KH);
  ushort_t* KlB  = (ushort_t*)(ws + F_KL);
  ushort_t* Vbf  = (ushort_t*)(ws + F_VBF);
  float*    Cm   = ws + F_C;
  ushort_t* APb  = (ushort_t*)(ws + F_APB);
  ushort_t* ycb  = (ushort_t*)(ws + F_YCB);
  ushort_t* VT   = (ushort_t*)(ws + F_VT);
  ushort_t* Wob  = (ushort_t*)(ws + F_WOB);
  float* divsum = ws + F_DIVS;
  float* Mst    = ws + F_MST;
  float* Lst    = ws + F_LST;
  float* entraw = ws + F_ENTR;
  float* ent    = ws + F_ENT;
  float* dep    = ws + F_DEP;
  float* Mp     = ws + F_MP;
  float* Lp     = ws + F_LP;
  float* sap    = ws + F_SAP;
  float* scp    = ws + F_SCP;
  float* yp0    = ws + F_Y;
  float* yp1    = ws + F_YP1;
  float* yp2    = ws + F_YP2;

  k_rownorm_bf<<<TT, 256, 0, stream>>>(x, Ubf);
  k_splitf<<<2048, 256, 0, stream>>>(x, xh, xl, 524288);
  k_splitf<<<1024, 256, 0, stream>>>(Wq, Wqh, Wql, 262144);
  k_splitf<<<1024, 256, 0, stream>>>(Wk, Wkh, Wkl, 262144);
  k_tobf<<<1024, 256, 0, stream>>>(Wv, Wvh, 262144);

  k_gemm<0, false><<<dim3(32, 32), 256, 0, stream>>>(Ubf, nullptr, Ubf, nullptr,
                                                     Cm, nullptr, nullptr, TT, TT, 1024);
  k_gemm<1, true><<<dim3(16, 32), 256, 0, stream>>>(xh, xl, Wqh, Wql,
                                                    nullptr, QhB, QlB, TT, 1024, 1024);
  k_gemm<1, true><<<dim3(16, 32), 256, 0, stream>>>(xh, xl, Wkh, Wkl,
                                                    nullptr, KhB, KlB, TT, 1024, 1024);
  k_gemm<2, false><<<dim3(16, 32), 256, 0, stream>>>(xh, nullptr, Wvh, nullptr,
                                                     nullptr, Vbf, nullptr, TT, 1024, 1024);
  k_tobf<<<1024, 256, 0, stream>>>(Wo, Wob, 262144);   // after K gemm (region overlay)

  k_divsum<<<TT, 256, 0, stream>>>(Cm, divsum);        // after gemms (stats overlay Wkl)
  k_apbf<<<TT, 256, 0, stream>>>(APb);

  k_phase1m<<<dim3(32, NH, 4), 256, 0, stream>>>(QhB, QlB, KhB, KlB, APb, Cm,
                                                 Mp, Lp, sap, scp);
  k_combine<<<64, 256, 0, stream>>>(Mp, Lp, sap, scp, divsum, Mst, Lst, entraw, dep);
  k_entnorm<<<NH, 256, 0, stream>>>(entraw, ent);
  k_vprime<<<dim3(32, NH), 256, 0, stream>>>(Vbf, dep, VT);
  k_phase2m<<<dim3(32, NH, 3), 256, 0, stream>>>(QhB, QlB, KhB, KlB, APb, VT,
                                                 Mst, Lst, dep, yp0, yp1, yp2, out2);
  k_ys<<<dim3(NH, TT / 2), 256, 0, stream>>>(yp0, yp1, yp2, ent, dep, W2, ycb);
  k_gemm<0, false><<<dim3(16, 32), 256, 0, stream>>>(ycb, nullptr, Wob, nullptr,
                                                     out, nullptr, nullptr, TT, 1024, 1024);
}

// Round 4
// 487.603 us; speedup vs baseline: 3.9219x; 1.5920x over previous
//
#include <hip/hip_runtime.h>
#include <math.h>

#define TT  2048
#define NH  8
#define DH  128
#define LNT 7.6246189861593985f   // ln(2048)

typedef unsigned short ushort_t;
typedef __bf16 bf16x8 __attribute__((ext_vector_type(8)));
typedef _Float16 f16x8 __attribute__((ext_vector_type(8)));
typedef float f32x4 __attribute__((ext_vector_type(4)));
typedef unsigned int uintx4 __attribute__((ext_vector_type(4)));

#define MFMA16(a, b, c)  __builtin_amdgcn_mfma_f32_16x16x32_bf16(a, b, c, 0, 0, 0)
#define MFMA16F(a, b, c) __builtin_amdgcn_mfma_f32_16x16x32_f16(a, b, c, 0, 0, 0)

__device__ __forceinline__ bf16x8 ld8(const ushort_t* p) {
  uintx4 v = *(const uintx4*)p;
  return __builtin_bit_cast(bf16x8, v);
}
__device__ __forceinline__ f16x8 ld8f(const ushort_t* p) {
  uintx4 v = *(const uintx4*)p;
  return __builtin_bit_cast(f16x8, v);
}
__device__ __forceinline__ ushort_t f2bf(float x) {
  unsigned u = __float_as_uint(x);
  return (ushort_t)((u + 0x7fffu + ((u >> 16) & 1u)) >> 16);
}
__device__ __forceinline__ float bf2f(ushort_t b) {
  return __uint_as_float(((unsigned)b) << 16);
}
__device__ __forceinline__ ushort_t f2h(float x) {
  return __builtin_bit_cast(ushort_t, (_Float16)x);
}
__device__ __forceinline__ float h2f(ushort_t b) {
  return (float)__builtin_bit_cast(_Float16, b);
}

// ---- workspace layout (float offsets). Max 16,777,216 floats = 64MB (< proven 69.2MB).
enum : size_t {
  F_XH   = 0u,          // xh bf16 [1M slots] -> yp0 fp32 [0..2M) in phase2
  F_XL   = 1048576u,
  F_UBF  = 2097152u,    // U bf16 -> ycb bf16 after C gemm
  F_QF   = 3145728u,    // Q fp16 [T,1024]
  F_KF   = 4194304u,    // K fp16
  F_VBF  = 5242880u,    // V bf16
  F_VT   = 6291456u,    // V'^T bf16 [H*DH, T]
  F_WQH  = 7340032u,    // weights (dead after gemms)
  F_WQL  = 7864320u,
  F_WKH  = 8388608u,
  F_WKL  = 8912896u,
  F_WVH  = 9437184u,
  F_WOB  = 9961472u,    // Wout bf16 (kept to the end)
  F_APH  = 10485760u,   // AP fp16 [T,T] = 2M slots
  F_C    = 12582912u,   // C fp32 [4M] -> yp1/yp2 in phase2
  // overlays
  F_YCB  = 2097152u,
  F_DIVS = 7340032u,    // stats overlay Wqh (dead after Q gemm)
  F_MST  = 7356416u,
  F_LST  = 7372800u,
  F_ENTR = 7389184u,
  F_ENT  = 7405568u,
  F_DEP  = 7421952u,
  F_MP   = 7438336u,    // [4][16384]
  F_LP   = 7503872u,
  F_SAP  = 7569408u,
  F_SCP  = 7634944u,    // ends 7700480 < 7864320
  F_YP0  = 0u,
  F_YP1  = 12582912u,
  F_YP2  = 14680064u,
  F_YP3  = 7864320u,    // overlay Wql..Wvh (dead after QKV gemms)
};

__device__ __forceinline__ float blockReduceSum256(float v) {
  __shared__ float sh[4];
  #pragma unroll
  for (int m = 1; m < 64; m <<= 1) v += __shfl_xor(v, m, 64);
  if ((threadIdx.x & 63) == 0) sh[threadIdx.x >> 6] = v;
  __syncthreads();
  float r = sh[0] + sh[1] + sh[2] + sh[3];
  __syncthreads();
  return r;
}

__global__ __launch_bounds__(256) void k_rownorm_bf(const float* __restrict__ x,
                                                    ushort_t* __restrict__ Ubf) {
  int t = blockIdx.x;
  const float* xr = x + (size_t)t * 1024;
  float ss = 0.f;
  for (int d = threadIdx.x; d < 1024; d += 256) { float v = xr[d]; ss += v * v; }
  ss = blockReduceSum256(ss);
  float inv = 1.f / fmaxf(sqrtf(ss), 1e-12f);
  for (int d = threadIdx.x; d < 1024; d += 256)
    Ubf[(size_t)t * 1024 + d] = f2bf(xr[d] * inv);
}

__global__ __launch_bounds__(256) void k_splitf(const float* __restrict__ s,
                                                ushort_t* __restrict__ hi,
                                                ushort_t* __restrict__ lo, int n4) {
  int i = blockIdx.x * 256 + threadIdx.x;
  if (i >= n4) return;
  float4 v = ((const float4*)s)[i];
  ushort_t h0 = f2bf(v.x), h1 = f2bf(v.y), h2 = f2bf(v.z), h3 = f2bf(v.w);
  uint2 hw, lw;
  hw.x = (unsigned)h0 | ((unsigned)h1 << 16);
  hw.y = (unsigned)h2 | ((unsigned)h3 << 16);
  lw.x = (unsigned)f2bf(v.x - bf2f(h0)) | ((unsigned)f2bf(v.y - bf2f(h1)) << 16);
  lw.y = (unsigned)f2bf(v.z - bf2f(h2)) | ((unsigned)f2bf(v.w - bf2f(h3)) << 16);
  ((uint2*)hi)[i] = hw;
  ((uint2*)lo)[i] = lw;
}

__global__ __launch_bounds__(256) void k_tobf(const float* __restrict__ s,
                                              ushort_t* __restrict__ d, int n4) {
  int i = blockIdx.x * 256 + threadIdx.x;
  if (i >= n4) return;
  float4 v = ((const float4*)s)[i];
  uint2 w;
  w.x = (unsigned)f2bf(v.x) | ((unsigned)f2bf(v.y) << 16);
  w.y = (unsigned)f2bf(v.z) | ((unsigned)f2bf(v.w) << 16);
  ((uint2*)d)[i] = w;
}

// NT MFMA GEMM: D[M,N] = A[M,K]*B[N,K]^T, 64x64 tile/block.
// MODE 0: f32 out; 2: bf16 out; 3: fp16 out.  BF3: A/B have lo parts (bf16x3).
template <int MODE, bool BF3>
__global__ __launch_bounds__(256) void k_gemm(
    const ushort_t* __restrict__ Ah, const ushort_t* __restrict__ Al,
    const ushort_t* __restrict__ Bh, const ushort_t* __restrict__ Bl,
    float* __restrict__ Df, ushort_t* __restrict__ Dh,
    int M, int N, int K) {
  int tid = threadIdx.x, lane = tid & 63, w = tid >> 6;
  int l15 = lane & 15, lg = lane >> 4;
  int m0 = blockIdx.y * 64 + w * 16, n0 = blockIdx.x * 64;
  f32x4 acc[4];
  #pragma unroll
  for (int ct = 0; ct < 4; ct++) acc[ct] = (f32x4)0.f;
  const ushort_t* ap = Ah + (size_t)(m0 + l15) * K + lg * 8;
  const ushort_t* alp = BF3 ? (Al + (size_t)(m0 + l15) * K + lg * 8) : nullptr;
  for (int k0 = 0; k0 < K; k0 += 32) {
    bf16x8 a = ld8(ap + k0);
    bf16x8 al;
    if (BF3) al = ld8(alp + k0);
    #pragma unroll
    for (int ct = 0; ct < 4; ct++) {
      size_t bo = (size_t)(n0 + ct * 16 + l15) * K + lg * 8 + k0;
      bf16x8 b = ld8(Bh + bo);
      acc[ct] = MFMA16(a, b, acc[ct]);
      if (BF3) {
        bf16x8 bl = ld8(Bl + bo);
        acc[ct] = MFMA16(al, b, acc[ct]);
        acc[ct] = MFMA16(a, bl, acc[ct]);
      }
    }
  }
  #pragma unroll
  for (int ct = 0; ct < 4; ct++) {
    #pragma unroll
    for (int r = 0; r < 4; r++) {
      size_t mm = m0 + lg * 4 + r, nn = n0 + ct * 16 + l15;
      float v = acc[ct][r];
      if (MODE == 0) Df[mm * N + nn] = v;
      if (MODE == 2) Dh[mm * N + nn] = f2bf(v);
      if (MODE == 3) Dh[mm * N + nn] = f2h(v);
    }
  }
}

__global__ __launch_bounds__(256) void k_divsum(const float* __restrict__ C,
                                                float* __restrict__ divsum) {
  int t = blockIdx.x;
  float s = 0.f;
  for (int j = threadIdx.x; j < TT; j += 256) s += C[(size_t)t * TT + j];
  s = blockReduceSum256(s);
  if (threadIdx.x == 0) divsum[t] = (float)TT - s;
}

__global__ __launch_bounds__(256) void k_aph(ushort_t* __restrict__ APh) {
  int t = blockIdx.x;
  for (int j = threadIdx.x; j < TT; j += 256) {
    int i = j >> 1;
    float invf = __expf((float)i * -0.017988946039016016f); // -ln(1e4)/512
    float ang = (float)t * invf;
    APh[(size_t)t * TT + j] = f2h((j & 1) ? cosf(ang) : sinf(ang));
  }
}

// ---- phase 1: fp16 QK^T, 8-wave blocks, K tile LDS-staged (XOR-swizzled) ----
__global__ __launch_bounds__(512, 4) void k_phase1m(
    const ushort_t* __restrict__ Qf, const ushort_t* __restrict__ Kf,
    const ushort_t* __restrict__ APh, const float* __restrict__ Cm,
    float* __restrict__ Mp, float* __restrict__ Lp,
    float* __restrict__ sap, float* __restrict__ scp) {
  int h = blockIdx.y, z = blockIdx.z;
  int tid = threadIdx.x, lane = tid & 63, w = tid >> 6;
  int l15 = lane & 15, lg = lane >> 4;
  int rowbase = blockIdx.x * 128 + w * 16;
  __shared__ __align__(16) ushort_t Ks[64 * 128];   // fp16, unit-swizzled

  f16x8 q[4];
  {
    const ushort_t* qp = Qf + (size_t)(rowbase + l15) * 1024 + h * DH + lg * 8;
    #pragma unroll
    for (int kc = 0; kc < 4; kc++) q[kc] = ld8f(qp + kc * 32);
  }
  // staging geometry: 1024 units of 16B; thread stages units n0 and n0+64
  int n0 = w * 128 + lane;
  int sr0 = n0 >> 4, su0 = n0 & 15, sr1 = sr0 + 4;
  int wo0 = sr0 * 128 + ((su0 ^ (sr0 & 7)) * 8);
  int wo1 = sr1 * 128 + ((su0 ^ (sr1 & 7)) * 8);
  const ushort_t* kg0 = Kf + (size_t)sr0 * 1024 + h * DH + su0 * 8;
  const ushort_t* kg1 = Kf + (size_t)sr1 * 1024 + h * DH + su0 * 8;

  float Mv[4], Lv[4], sae[4], snc[4];
  #pragma unroll
  for (int r = 0; r < 4; r++) { Mv[r] = -1e30f; Lv[r] = 0.f; sae[r] = 0.f; snc[r] = 0.f; }

  for (int s0 = z * 512; s0 < z * 512 + 512; s0 += 64) {
    uintx4 ka = *(const uintx4*)(kg0 + (size_t)s0 * 1024);
    uintx4 kb = *(const uintx4*)(kg1 + (size_t)s0 * 1024);
    __syncthreads();
    *(uintx4*)(Ks + wo0) = ka;
    *(uintx4*)(Ks + wo1) = kb;
    __syncthreads();
    f32x4 acc[4];
    #pragma unroll
    for (int ct = 0; ct < 4; ct++) acc[ct] = (f32x4)0.f;
    #pragma unroll
    for (int ct = 0; ct < 4; ct++) {
      int row = ct * 16 + l15, rb = row * 128, rs = row & 7;
      #pragma unroll
      for (int kc = 0; kc < 4; kc++) {
        f16x8 b = ld8f(Ks + rb + (((kc * 4 + lg) ^ rs) * 8));
        acc[ct] = MFMA16F(q[kc], b, acc[ct]);
      }
    }
    #pragma unroll
    for (int r = 0; r < 4; r++) {
      int t = rowbase + lg * 4 + r;
      float e0 = acc[0][r] + h2f(APh[(size_t)t * TT + s0 +  0 + l15]);
      float e1 = acc[1][r] + h2f(APh[(size_t)t * TT + s0 + 16 + l15]);
      float e2 = acc[2][r] + h2f(APh[(size_t)t * TT + s0 + 32 + l15]);
      float e3 = acc[3][r] + h2f(APh[(size_t)t * TT + s0 + 48 + l15]);
      float c0 = Cm[(size_t)t * TT + s0 +  0 + l15];
      float c1 = Cm[(size_t)t * TT + s0 + 16 + l15];
      float c2 = Cm[(size_t)t * TT + s0 + 32 + l15];
      float c3 = Cm[(size_t)t * TT + s0 + 48 + l15];
      float m2 = fmaxf(fmaxf(e0, e1), fmaxf(e2, e3));
      float newM = fmaxf(Mv[r], m2);
      float rsc = __expf(Mv[r] - newM);
      float p0 = __expf(e0 - newM), p1 = __expf(e1 - newM);
      float p2 = __expf(e2 - newM), p3 = __expf(e3 - newM);
      Lv[r]  = Lv[r]  * rsc + (p0 + p1) + (p2 + p3);
      sae[r] = sae[r] * rsc + (p0 * e0 + p1 * e1) + (p2 * e2 + p3 * e3);
      snc[r] = snc[r] * rsc + (p0 * c0 + p1 * c1) + (p2 * c2 + p3 * c3);
      Mv[r] = newM;
    }
  }
  #pragma unroll
  for (int r = 0; r < 4; r++) {
    #pragma unroll
    for (int m = 1; m < 16; m <<= 1) {
      float Mo = __shfl_xor(Mv[r], m, 64);
      float Lo = __shfl_xor(Lv[r], m, 64);
      float so = __shfl_xor(sae[r], m, 64);
      float co = __shfl_xor(snc[r], m, 64);
      float nM = fmaxf(Mv[r], Mo);
      float s1 = __expf(Mv[r] - nM), s2 = __expf(Mo - nM);
      Lv[r]  = Lv[r]  * s1 + Lo * s2;
      sae[r] = sae[r] * s1 + so * s2;
      snc[r] = snc[r] * s1 + co * s2;
      Mv[r] = nM;
    }
  }
  if (l15 == 0) {
    #pragma unroll
    for (int r = 0; r < 4; r++) {
      int t = rowbase + lg * 4 + r;
      size_t idx = (size_t)z * (NH * TT) + h * TT + t;
      Mp[idx] = Mv[r]; Lp[idx] = Lv[r]; sap[idx] = sae[r]; scp[idx] = snc[r];
    }
  }
}

__global__ __launch_bounds__(256) void k_combine(
    const float* __restrict__ Mp, const float* __restrict__ Lp,
    const float* __restrict__ sap, const float* __restrict__ scp,
    const float* __restrict__ divsum,
    float* __restrict__ Mst, float* __restrict__ Lst,
    float* __restrict__ entraw, float* __restrict__ dep) {
  int i = blockIdx.x * 256 + threadIdx.x;
  if (i >= NH * TT) return;
  float M = -1e30f, L = 0.f, sa = 0.f, sc = 0.f;
  #pragma unroll
  for (int c = 0; c < 4; c++) {
    size_t idx = (size_t)c * (NH * TT) + i;
    float Mc = Mp[idx], Lc = Lp[idx], sac = sap[idx], scc = scp[idx];
    float nM = fmaxf(M, Mc);
    float s1 = __expf(M - nM), s2 = __expf(Mc - nM);
    L = L * s1 + Lc * s2;
    sa = sa * s1 + sac * s2;
    sc = sc * s1 + scc * s2;
    M = nM;
  }
  float logL = __logf(L);
  Mst[i] = M; Lst[i] = logL;
  entraw[i] = (M + logL - sa / L) * (1.0f / LNT);
  int t = i & (TT - 1);
  dep[i] = (1.f - sc / L) / divsum[t];
}

__global__ __launch_bounds__(256) void k_entnorm(const float* __restrict__ entraw,
                                                 float* __restrict__ ent) {
  int h = blockIdx.x;
  float s = 0.f;
  for (int t = threadIdx.x; t < TT; t += 256) s += fabsf(entraw[h * TT + t]);
  s = blockReduceSum256(s);
  float inv = 1.f / fmaxf(s, 1e-12f);
  for (int t = threadIdx.x; t < TT; t += 256) ent[h * TT + t] = entraw[h * TT + t] * inv;
}

// V'^T[h][e][s] = bf16( V[s][h*DH+e] * (1+dep[h][s]) )
__global__ __launch_bounds__(256) void k_vprime(const ushort_t* __restrict__ Vbf,
                                                const float* __restrict__ dep,
                                                ushort_t* __restrict__ VT) {
  int h = blockIdx.y, s0 = blockIdx.x * 64;
  __shared__ float tile[64][130];
  int tid = threadIdx.x;
  for (int idx = tid; idx < 64 * 64; idx += 256) {
    int r = idx >> 6, c2 = (idx & 63) * 2;
    unsigned u = *(const unsigned*)&Vbf[(size_t)(s0 + r) * 1024 + h * DH + c2];
    tile[r][c2] = bf2f((ushort_t)(u & 0xffffu));
    tile[r][c2 + 1] = bf2f((ushort_t)(u >> 16));
  }
  __syncthreads();
  int e = tid >> 1, sh = (tid & 1) * 32;
  #pragma unroll
  for (int g = 0; g < 8; g++) {
    int sb = sh + g * 4;
    float v0 = tile[sb + 0][e] * (1.f + dep[h * TT + s0 + sb + 0]);
    float v1 = tile[sb + 1][e] * (1.f + dep[h * TT + s0 + sb + 1]);
    float v2 = tile[sb + 2][e] * (1.f + dep[h * TT + s0 + sb + 2]);
    float v3 = tile[sb + 3][e] * (1.f + dep[h * TT + s0 + sb + 3]);
    uint2 wv;
    wv.x = (unsigned)f2bf(v0) | ((unsigned)f2bf(v1) << 16);
    wv.y = (unsigned)f2bf(v2) | ((unsigned)f2bf(v3) << 16);
    *(uint2*)&VT[(size_t)(h * DH + e) * TT + s0 + sb] = wv;
  }
}

// ---- phase 2: fp16 QK^T, LDS-staged K & V', 8-wave blocks, z=4 partial-y ----
__global__ __launch_bounds__(512, 4) void k_phase2m(
    const ushort_t* __restrict__ Qf, const ushort_t* __restrict__ Kf,
    const ushort_t* __restrict__ APh, const ushort_t* __restrict__ VT,
    const float* __restrict__ Mst, const float* __restrict__ Lst,
    const float* __restrict__ dep,
    float* __restrict__ yp0, float* __restrict__ yp1,
    float* __restrict__ yp2, float* __restrict__ yp3,
    float* __restrict__ out2) {
  int h = blockIdx.y, z = blockIdx.z;
  int tid = threadIdx.x, lane = tid & 63, w = tid >> 6;
  int l15 = lane & 15, lg = lane >> 4;
  int rowbase = blockIdx.x * 128 + w * 16;
  bool last = (h == NH - 1);
  float* yp = (z == 0) ? yp0 : (z == 1) ? yp1 : (z == 2) ? yp2 : yp3;

  __shared__ __align__(16) ushort_t Ks[64 * 128];   // fp16 K tile
  __shared__ __align__(16) ushort_t Vs[128 * 64];   // bf16 V' tile [e][s]
  __shared__ __align__(16) ushort_t Pst[8][16][72]; // bf16 P, per wave

  f16x8 q[4];
  {
    const ushort_t* qp = Qf + (size_t)(rowbase + l15) * 1024 + h * DH + lg * 8;
    #pragma unroll
    for (int kc = 0; kc < 4; kc++) q[kc] = ld8f(qp + kc * 32);
  }
  float ml[4];
  #pragma unroll
  for (int r = 0; r < 4; r++) {
    int t = rowbase + lg * 4 + r;
    ml[r] = Mst[h * TT + t] + Lst[h * TT + t];
  }
  // staging geometry
  int n0 = w * 128 + lane;
  int sr0 = n0 >> 4, su0 = n0 & 15, sr1 = sr0 + 4;
  int kwo0 = sr0 * 128 + ((su0 ^ (sr0 & 7)) * 8);
  int kwo1 = sr1 * 128 + ((su0 ^ (sr1 & 7)) * 8);
  const ushort_t* kg0 = Kf + (size_t)sr0 * 1024 + h * DH + su0 * 8;
  const ushort_t* kg1 = Kf + (size_t)sr1 * 1024 + h * DH + su0 * 8;
  int ve0 = n0 >> 3, vu0 = n0 & 7;
  int vwo0 = ve0 * 64 + ((vu0 ^ (ve0 & 7)) * 8);
  int vwo1 = vwo0 + 512;                          // (ve0+8)&7 == ve0&7
  const ushort_t* vg0 = VT + (size_t)(h * DH + ve0) * TT + vu0 * 8;
  const ushort_t* vg1 = vg0 + (size_t)8 * TT;

  f32x4 yacc[8];
  #pragma unroll
  for (int et = 0; et < 8; et++) yacc[et] = (f32x4)0.f;

  for (int s0 = z * 512; s0 < z * 512 + 512; s0 += 64) {
    uintx4 ka = *(const uintx4*)(kg0 + (size_t)s0 * 1024);
    uintx4 kb = *(const uintx4*)(kg1 + (size_t)s0 * 1024);
    uintx4 va = *(const uintx4*)(vg0 + s0);
    uintx4 vb = *(const uintx4*)(vg1 + s0);
    __syncthreads();
    *(uintx4*)(Ks + kwo0) = ka;
    *(uintx4*)(Ks + kwo1) = kb;
    *(uintx4*)(Vs + vwo0) = va;
    *(uintx4*)(Vs + vwo1) = vb;
    __syncthreads();
    f32x4 acc[4];
    #pragma unroll
    for (int ct = 0; ct < 4; ct++) acc[ct] = (f32x4)0.f;
    #pragma unroll
    for (int ct = 0; ct < 4; ct++) {
      int row = ct * 16 + l15, rb = row * 128, rs = row & 7;
      #pragma unroll
      for (int kc = 0; kc < 4; kc++) {
        f16x8 b = ld8f(Ks + rb + (((kc * 4 + lg) ^ rs) * 8));
        acc[ct] = MFMA16F(q[kc], b, acc[ct]);
      }
    }
    float dv[4];
    if (last) {
      #pragma unroll
      for (int ct = 0; ct < 4; ct++) dv[ct] = dep[(NH - 1) * TT + s0 + ct * 16 + l15];
    }
    #pragma unroll
    for (int ct = 0; ct < 4; ct++) {
      #pragma unroll
      for (int r = 0; r < 4; r++) {
        int t = rowbase + lg * 4 + r;
        float e = acc[ct][r] + h2f(APh[(size_t)t * TT + s0 + ct * 16 + l15]);
        float a = __expf(e - ml[r]);
        Pst[w][lg * 4 + r][ct * 16 + l15] = f2bf(a);
        if (last) out2[(size_t)t * TT + s0 + ct * 16 + l15] = a * (1.f + dv[ct]);
      }
    }
    asm volatile("" ::: "memory");   // wave-internal: P writes before P reads
    #pragma unroll
    for (int c = 0; c < 2; c++) {
      bf16x8 ap = *(const bf16x8*)&Pst[w][l15][c * 32 + lg * 8];
      #pragma unroll
      for (int et = 0; et < 8; et++) {
        int e = et * 16 + l15;
        bf16x8 bv = ld8(Vs + e * 64 + (((c * 4 + lg) ^ (l15 & 7)) * 8));
        yacc[et] = MFMA16(ap, bv, yacc[et]);
      }
    }
    asm volatile("" ::: "memory");
  }
  #pragma unroll
  for (int et = 0; et < 8; et++)
    #pragma unroll
    for (int r = 0; r < 4; r++)
      yp[((size_t)h * TT + rowbase + lg * 4 + r) * DH + et * 16 + l15] = yacc[et][r];
}

// y_s = [sum(yp0..3) | ent | dep] @ W2^T -> ycat bf16
__global__ __launch_bounds__(256) void k_ys(const float* __restrict__ yp0,
                                            const float* __restrict__ yp1,
                                            const float* __restrict__ yp2,
                                            const float* __restrict__ yp3,
                                            const float* __restrict__ ent,
                                            const float* __restrict__ dep,
                                            const float* __restrict__ W2,
                                            ushort_t* __restrict__ ycatb) {
  int h = blockIdx.x, t0 = blockIdx.y * 2;
  int tid = threadIdx.x;
  __shared__ float yls[2][128];
  {
    int rr = tid >> 7, cc = tid & 127;
    size_t idx = ((size_t)h * TT + t0 + rr) * DH + cc;
    yls[rr][cc] = (yp0[idx] + yp1[idx]) + (yp2[idx] + yp3[idx]);
  }
  __syncthreads();
  int trow = tid >> 7, o = tid & 127;
  int t = t0 + trow;
  float et = ent[h * TT + t], dp = dep[h * TT + t];
  float s = 0.f;
  #pragma unroll 4
  for (int f = 0; f < DH; f++) s += yls[trow][f] * W2[o * 130 + f];
  s += et * W2[o * 130 + 128] + dp * W2[o * 130 + 129];
  ycatb[(size_t)t * 1024 + h * DH + o] = f2bf(s);
}

extern "C" void kernel_launch(void* const* d_in, const int* in_sizes, int n_in,
                              void* d_out, int out_size, void* d_ws, size_t ws_size,
                              hipStream_t stream) {
  const float* x  = (const float*)d_in[0];
  const float* Wq = (const float*)d_in[1];
  const float* Wk = (const float*)d_in[2];
  const float* Wv = (const float*)d_in[3];
  const float* W2 = (const float*)d_in[4];
  const float* Wo = (const float*)d_in[5];
  float* out  = (float*)d_out;                  // [T,1024]
  float* out2 = out + (size_t)TT * 1024;        // att_win[-1] [T,T]
  float* ws = (float*)d_ws;

  ushort_t* xh   = (ushort_t*)(ws + F_XH);
  ushort_t* xl   = (ushort_t*)(ws + F_XL);
  ushort_t* Ubf  = (ushort_t*)(ws + F_UBF);
  ushort_t* Qf   = (ushort_t*)(ws + F_QF);
  ushort_t* Kf   = (ushort_t*)(ws + F_KF);
  ushort_t* Vbf  = (ushort_t*)(ws + F_VBF);
  ushort_t* VT   = (ushort_t*)(ws + F_VT);
  ushort_t* Wqh  = (ushort_t*)(ws + F_WQH);
  ushort_t* Wql  = (ushort_t*)(ws + F_WQL);
  ushort_t* Wkh  = (ushort_t*)(ws + F_WKH);
  ushort_t* Wkl  = (ushort_t*)(ws + F_WKL);
  ushort_t* Wvh  = (ushort_t*)(ws + F_WVH);
  ushort_t* Wob  = (ushort_t*)(ws + F_WOB);
  ushort_t* APh  = (ushort_t*)(ws + F_APH);
  float*    Cm   = ws + F_C;
  ushort_t* ycb  = (ushort_t*)(ws + F_YCB);
  float* divsum = ws + F_DIVS;
  float* Mst    = ws + F_MST;
  float* Lst    = ws + F_LST;
  float* entraw = ws + F_ENTR;
  float* ent    = ws + F_ENT;
  float* dep    = ws + F_DEP;
  float* Mp     = ws + F_MP;
  float* Lp     = ws + F_LP;
  float* sap    = ws + F_SAP;
  float* scp    = ws + F_SCP;
  float* yp0    = ws + F_YP0;
  float* yp1    = ws + F_YP1;
  float* yp2    = ws + F_YP2;
  float* yp3    = ws + F_YP3;

  k_rownorm_bf<<<TT, 256, 0, stream>>>(x, Ubf);
  k_splitf<<<2048, 256, 0, stream>>>(x, xh, xl, 524288);
  k_splitf<<<1024, 256, 0, stream>>>(Wq, Wqh, Wql, 262144);
  k_splitf<<<1024, 256, 0, stream>>>(Wk, Wkh, Wkl, 262144);
  k_tobf<<<1024, 256, 0, stream>>>(Wv, Wvh, 262144);

  k_gemm<0, false><<<dim3(32, 32), 256, 0, stream>>>(Ubf, nullptr, Ubf, nullptr,
                                                     Cm, nullptr, TT, TT, 1024);
  k_gemm<3, true><<<dim3(16, 32), 256, 0, stream>>>(xh, xl, Wqh, Wql,
                                                    nullptr, Qf, TT, 1024, 1024);
  k_gemm<3, true><<<dim3(16, 32), 256, 0, stream>>>(xh, xl, Wkh, Wkl,
                                                    nullptr, Kf, TT, 1024, 1024);
  k_gemm<2, false><<<dim3(16, 32), 256, 0, stream>>>(xh, nullptr, Wvh, nullptr,
                                                     nullptr, Vbf, TT, 1024, 1024);
  k_tobf<<<1024, 256, 0, stream>>>(Wo, Wob, 262144);

  k_divsum<<<TT, 256, 0, stream>>>(Cm, divsum);       // stats overlay Wqh (dead)
  k_aph<<<TT, 256, 0, stream>>>(APh);

  k_phase1m<<<dim3(16, NH, 4), 512, 0, stream>>>(Qf, Kf, APh, Cm, Mp, Lp, sap, scp);
  k_combine<<<64, 256, 0, stream>>>(Mp, Lp, sap, scp, divsum, Mst, Lst, entraw, dep);
  k_entnorm<<<NH, 256, 0, stream>>>(entraw, ent);
  k_vprime<<<dim3(32, NH), 256, 0, stream>>>(Vbf, dep, VT);
  k_phase2m<<<dim3(16, NH, 4), 512, 0, stream>>>(Qf, Kf, APh, VT, Mst, Lst, dep,
                                                 yp0, yp1, yp2, yp3, out2);
  k_ys<<<dim3(NH, TT / 2), 256, 0, stream>>>(yp0, yp1, yp2, yp3, ent, dep, W2, ycb);
  k_gemm<0, false><<<dim3(16, 32), 256, 0, stream>>>(ycb, nullptr, Wob, nullptr,
                                                     out, nullptr, TT, 1024, 1024);
}

// Round 5
// 257.772 us; speedup vs baseline: 7.4187x; 1.8916x over previous
//
#include <hip/hip_runtime.h>
#include <math.h>

#define TT  2048
#define NH  8
#define DH  128
#define LNT 7.6246189861593985f   // ln(2048)

typedef unsigned short ushort_t;
typedef __bf16 bf16x8 __attribute__((ext_vector_type(8)));
typedef _Float16 f16x8 __attribute__((ext_vector_type(8)));
typedef float f32x4 __attribute__((ext_vector_type(4)));
typedef unsigned int uintx4 __attribute__((ext_vector_type(4)));

#define MFMA16(a, b, c)  __builtin_amdgcn_mfma_f32_16x16x32_bf16(a, b, c, 0, 0, 0)
#define MFMA16F(a, b, c) __builtin_amdgcn_mfma_f32_16x16x32_f16(a, b, c, 0, 0, 0)

__device__ __forceinline__ bf16x8 ld8(const ushort_t* p) {
  uintx4 v = *(const uintx4*)p;
  return __builtin_bit_cast(bf16x8, v);
}
__device__ __forceinline__ f16x8 ld8f(const ushort_t* p) {
  uintx4 v = *(const uintx4*)p;
  return __builtin_bit_cast(f16x8, v);
}
__device__ __forceinline__ ushort_t f2bf(float x) {
  unsigned u = __float_as_uint(x);
  return (ushort_t)((u + 0x7fffu + ((u >> 16) & 1u)) >> 16);
}
__device__ __forceinline__ float bf2f(ushort_t b) {
  return __uint_as_float(((unsigned)b) << 16);
}
__device__ __forceinline__ ushort_t f2h(float x) {
  return __builtin_bit_cast(ushort_t, (_Float16)x);
}
__device__ __forceinline__ float h2f(ushort_t b) {
  return (float)__builtin_bit_cast(_Float16, b);
}

// ---- workspace layout (float offsets). Total 16,777,216 floats = 64MB (proven safe R4).
enum : size_t {
  F_XF   = 0u,          // x fp16 [1M] -> yp0 fp32 [0,2M) in phase2
  F_UF   = 1048576u,    // U fp16 [1M]
  F_QF   = 2097152u,    // Q fp16
  F_KF   = 3145728u,    // K fp16
  F_VBF  = 4194304u,    // V bf16
  F_VT   = 5242880u,    // V'^T bf16 [H*DH, T]
  F_YCF  = 6291456u,    // ycat fp16
  F_WCAT = 7340032u,    // Wq|Wk|Wv fp16 [3072,1024] = 1.5M -> yp3 [7340032, 9437184)
  F_WOF  = 9437184u,    // Wout fp16 [0.5M], kept to the end
  F_DIVS = 9961472u,
  F_MST  = 9963520u,
  F_LST  = 9979904u,
  F_ENTR = 9996288u,
  F_ENT  = 10012672u,
  F_DEP  = 10029056u,
  F_MP   = 10045440u,   // [4][16384] partial stats
  F_LP   = 10110976u,
  F_SAP  = 10176512u,
  F_SCP  = 10242048u,   // ends 10307584 < 10485760
  F_APH  = 10485760u,   // AP fp16 [T,T] = 2M floats
  F_C    = 12582912u,   // C fp32 [4M] -> yp1/yp2 in phase2
  F_YP0  = 0u,
  F_YP1  = 12582912u,
  F_YP2  = 14680064u,
  F_YP3  = 7340032u,
};

__device__ __forceinline__ float blockReduceSum256(float v) {
  __shared__ float sh[4];
  #pragma unroll
  for (int m = 1; m < 64; m <<= 1) v += __shfl_xor(v, m, 64);
  if ((threadIdx.x & 63) == 0) sh[threadIdx.x >> 6] = v;
  __syncthreads();
  float r = sh[0] + sh[1] + sh[2] + sh[3];
  __syncthreads();
  return r;
}

__global__ __launch_bounds__(256) void k_rownorm_f16(const float* __restrict__ x,
                                                     ushort_t* __restrict__ Uf) {
  int t = blockIdx.x;
  const float* xr = x + (size_t)t * 1024;
  float ss = 0.f;
  for (int d = threadIdx.x; d < 1024; d += 256) { float v = xr[d]; ss += v * v; }
  ss = blockReduceSum256(ss);
  float inv = 1.f / fmaxf(sqrtf(ss), 1e-12f);
  for (int d = threadIdx.x; d < 1024; d += 256)
    Uf[(size_t)t * 1024 + d] = f2h(xr[d] * inv);
}

__global__ __launch_bounds__(256) void k_tof16(const float* __restrict__ s,
                                               ushort_t* __restrict__ d, int n4) {
  int i = blockIdx.x * 256 + threadIdx.x;
  if (i >= n4) return;
  float4 v = ((const float4*)s)[i];
  uint2 w;
  w.x = (unsigned)f2h(v.x) | ((unsigned)f2h(v.y) << 16);
  w.y = (unsigned)f2h(v.z) | ((unsigned)f2h(v.w) << 16);
  ((uint2*)d)[i] = w;
}

// ---- m97-style NT GEMM: D[M,N] = A[M,K] * B[N,K]^T, fp16 in, 128x128 tile, BK=64.
// LDS linear dest via global_load_lds(16B) + pre-swizzled global source;
// ds_read_b128 with matching XOR -> conflict-free (T2/G21 both-sides rule).
// MODE: 0 f32 out; 1 fp16 out; 2 bf16 out; 3 QKV split (fp16,fp16,bf16).
template <int MODE>
__global__ __launch_bounds__(256) void k_gemm(
    const ushort_t* __restrict__ A, const ushort_t* __restrict__ B,
    float* __restrict__ Df, ushort_t* __restrict__ Dh,
    ushort_t* __restrict__ Dq, ushort_t* __restrict__ Dk, ushort_t* __restrict__ Dv,
    int M, int N, int K) {
  __shared__ __align__(16) ushort_t As[128 * 64];
  __shared__ __align__(16) ushort_t Bs[128 * 64];
  int tid = threadIdx.x, lane = tid & 63, w = tid >> 6;
  int l15 = lane & 15, lg = lane >> 4;
  int wr = w >> 1, wc = w & 1;
  int m0 = blockIdx.y * 128, n0 = blockIdx.x * 128;

  // staging: unit u=(4w+j)*64+lane holds global (row=u>>3, kcol8=(u&7)^(row&7))
  const ushort_t* ga[4];
  const ushort_t* gb[4];
  ushort_t* la[4];
  ushort_t* lb[4];
  #pragma unroll
  for (int j = 0; j < 4; j++) {
    int u = (4 * w + j) * 64 + lane;
    int row = u >> 3;
    int kc8 = (u & 7) ^ (row & 7);
    ga[j] = A + (size_t)(m0 + row) * K + kc8 * 8;
    gb[j] = B + (size_t)(n0 + row) * K + kc8 * 8;
    la[j] = As + (4 * w + j) * 512;
    lb[j] = Bs + (4 * w + j) * 512;
  }

  f32x4 acc[4][4];
  #pragma unroll
  for (int i = 0; i < 4; i++)
    #pragma unroll
    for (int ct = 0; ct < 4; ct++) acc[i][ct] = (f32x4)0.f;

  for (int k0 = 0; k0 < K; k0 += 64) {
    __syncthreads();
    #pragma unroll
    for (int j = 0; j < 4; j++) {
      __builtin_amdgcn_global_load_lds(
          (const __attribute__((address_space(1))) void*)(ga[j] + k0),
          (__attribute__((address_space(3))) void*)la[j], 16, 0, 0);
      __builtin_amdgcn_global_load_lds(
          (const __attribute__((address_space(1))) void*)(gb[j] + k0),
          (__attribute__((address_space(3))) void*)lb[j], 16, 0, 0);
    }
    __syncthreads();
    #pragma unroll
    for (int kc = 0; kc < 2; kc++) {
      f16x8 af[4], bfr[4];
      #pragma unroll
      for (int i = 0; i < 4; i++) {
        int ra = wr * 64 + i * 16 + l15;
        af[i] = ld8f(As + (ra * 8 + ((kc * 4 + lg) ^ (ra & 7))) * 8);
        int rb = wc * 64 + i * 16 + l15;
        bfr[i] = ld8f(Bs + (rb * 8 + ((kc * 4 + lg) ^ (rb & 7))) * 8);
      }
      #pragma unroll
      for (int i = 0; i < 4; i++)
        #pragma unroll
        for (int ct = 0; ct < 4; ct++)
          acc[i][ct] = MFMA16F(af[i], bfr[ct], acc[i][ct]);
    }
  }
  #pragma unroll
  for (int i = 0; i < 4; i++) {
    #pragma unroll
    for (int ct = 0; ct < 4; ct++) {
      #pragma unroll
      for (int r = 0; r < 4; r++) {
        size_t mm = m0 + wr * 64 + i * 16 + lg * 4 + r;
        size_t nn = n0 + wc * 64 + ct * 16 + l15;
        float v = acc[i][ct][r];
        if (MODE == 0) Df[mm * N + nn] = v;
        if (MODE == 1) Dh[mm * N + nn] = f2h(v);
        if (MODE == 2) Dh[mm * N + nn] = f2bf(v);
        if (MODE == 3) {
          if (nn < 1024) Dq[mm * 1024 + nn] = f2h(v);
          else if (nn < 2048) Dk[mm * 1024 + nn - 1024] = f2h(v);
          else Dv[mm * 1024 + nn - 2048] = f2bf(v);
        }
      }
    }
  }
}

__global__ __launch_bounds__(256) void k_divsum(const float* __restrict__ C,
                                                float* __restrict__ divsum) {
  int t = blockIdx.x;
  float s = 0.f;
  for (int j = threadIdx.x; j < TT; j += 256) s += C[(size_t)t * TT + j];
  s = blockReduceSum256(s);
  if (threadIdx.x == 0) divsum[t] = (float)TT - s;
}

__global__ __launch_bounds__(256) void k_aph(ushort_t* __restrict__ APh) {
  int t = blockIdx.x;
  for (int j = threadIdx.x; j < TT; j += 256) {
    int i = j >> 1;
    float invf = __expf((float)i * -0.017988946039016016f); // -ln(1e4)/512
    float ang = (float)t * invf;
    APh[(size_t)t * TT + j] = f2h((j & 1) ? cosf(ang) : sinf(ang));
  }
}

// ---- phase 1: fp16 QK^T, 8-wave blocks, K tile LDS-staged (XOR-swizzled) ----
__global__ __launch_bounds__(512, 4) void k_phase1m(
    const ushort_t* __restrict__ Qf, const ushort_t* __restrict__ Kf,
    const ushort_t* __restrict__ APh, const float* __restrict__ Cm,
    float* __restrict__ Mp, float* __restrict__ Lp,
    float* __restrict__ sap, float* __restrict__ scp) {
  int h = blockIdx.y, z = blockIdx.z;
  int tid = threadIdx.x, lane = tid & 63, w = tid >> 6;
  int l15 = lane & 15, lg = lane >> 4;
  int rowbase = blockIdx.x * 128 + w * 16;
  __shared__ __align__(16) ushort_t Ks[64 * 128];   // fp16, unit-swizzled

  f16x8 q[4];
  {
    const ushort_t* qp = Qf + (size_t)(rowbase + l15) * 1024 + h * DH + lg * 8;
    #pragma unroll
    for (int kc = 0; kc < 4; kc++) q[kc] = ld8f(qp + kc * 32);
  }
  int n0 = w * 128 + lane;
  int sr0 = n0 >> 4, su0 = n0 & 15, sr1 = sr0 + 4;
  int wo0 = sr0 * 128 + ((su0 ^ (sr0 & 7)) * 8);
  int wo1 = sr1 * 128 + ((su0 ^ (sr1 & 7)) * 8);
  const ushort_t* kg0 = Kf + (size_t)sr0 * 1024 + h * DH + su0 * 8;
  const ushort_t* kg1 = Kf + (size_t)sr1 * 1024 + h * DH + su0 * 8;

  float Mv[4], Lv[4], sae[4], snc[4];
  #pragma unroll
  for (int r = 0; r < 4; r++) { Mv[r] = -1e30f; Lv[r] = 0.f; sae[r] = 0.f; snc[r] = 0.f; }

  for (int s0 = z * 512; s0 < z * 512 + 512; s0 += 64) {
    uintx4 ka = *(const uintx4*)(kg0 + (size_t)s0 * 1024);
    uintx4 kb = *(const uintx4*)(kg1 + (size_t)s0 * 1024);
    __syncthreads();
    *(uintx4*)(Ks + wo0) = ka;
    *(uintx4*)(Ks + wo1) = kb;
    __syncthreads();
    f32x4 acc[4];
    #pragma unroll
    for (int ct = 0; ct < 4; ct++) acc[ct] = (f32x4)0.f;
    #pragma unroll
    for (int ct = 0; ct < 4; ct++) {
      int row = ct * 16 + l15, rb = row * 128, rs = row & 7;
      #pragma unroll
      for (int kc = 0; kc < 4; kc++) {
        f16x8 b = ld8f(Ks + rb + (((kc * 4 + lg) ^ rs) * 8));
        acc[ct] = MFMA16F(q[kc], b, acc[ct]);
      }
    }
    #pragma unroll
    for (int r = 0; r < 4; r++) {
      int t = rowbase + lg * 4 + r;
      float e0 = acc[0][r] + h2f(APh[(size_t)t * TT + s0 +  0 + l15]);
      float e1 = acc[1][r] + h2f(APh[(size_t)t * TT + s0 + 16 + l15]);
      float e2 = acc[2][r] + h2f(APh[(size_t)t * TT + s0 + 32 + l15]);
      float e3 = acc[3][r] + h2f(APh[(size_t)t * TT + s0 + 48 + l15]);
      float c0 = Cm[(size_t)t * TT + s0 +  0 + l15];
      float c1 = Cm[(size_t)t * TT + s0 + 16 + l15];
      float c2 = Cm[(size_t)t * TT + s0 + 32 + l15];
      float c3 = Cm[(size_t)t * TT + s0 + 48 + l15];
      float m2 = fmaxf(fmaxf(e0, e1), fmaxf(e2, e3));
      float newM = fmaxf(Mv[r], m2);
      float rsc = __expf(Mv[r] - newM);
      float p0 = __expf(e0 - newM), p1 = __expf(e1 - newM);
      float p2 = __expf(e2 - newM), p3 = __expf(e3 - newM);
      Lv[r]  = Lv[r]  * rsc + (p0 + p1) + (p2 + p3);
      sae[r] = sae[r] * rsc + (p0 * e0 + p1 * e1) + (p2 * e2 + p3 * e3);
      snc[r] = snc[r] * rsc + (p0 * c0 + p1 * c1) + (p2 * c2 + p3 * c3);
      Mv[r] = newM;
    }
  }
  #pragma unroll
  for (int r = 0; r < 4; r++) {
    #pragma unroll
    for (int m = 1; m < 16; m <<= 1) {
      float Mo = __shfl_xor(Mv[r], m, 64);
      float Lo = __shfl_xor(Lv[r], m, 64);
      float so = __shfl_xor(sae[r], m, 64);
      float co = __shfl_xor(snc[r], m, 64);
      float nM = fmaxf(Mv[r], Mo);
      float s1 = __expf(Mv[r] - nM), s2 = __expf(Mo - nM);
      Lv[r]  = Lv[r]  * s1 + Lo * s2;
      sae[r] = sae[r] * s1 + so * s2;
      snc[r] = snc[r] * s1 + co * s2;
      Mv[r] = nM;
    }
  }
  if (l15 == 0) {
    #pragma unroll
    for (int r = 0; r < 4; r++) {
      int t = rowbase + lg * 4 + r;
      size_t idx = (size_t)z * (NH * TT) + h * TT + t;
      Mp[idx] = Mv[r]; Lp[idx] = Lv[r]; sap[idx] = sae[r]; scp[idx] = snc[r];
    }
  }
}

__global__ __launch_bounds__(256) void k_combine(
    const float* __restrict__ Mp, const float* __restrict__ Lp,
    const float* __restrict__ sap, const float* __restrict__ scp,
    const float* __restrict__ divsum,
    float* __restrict__ Mst, float* __restrict__ Lst,
    float* __restrict__ entraw, float* __restrict__ dep) {
  int i = blockIdx.x * 256 + threadIdx.x;
  if (i >= NH * TT) return;
  float M = -1e30f, L = 0.f, sa = 0.f, sc = 0.f;
  #pragma unroll
  for (int c = 0; c < 4; c++) {
    size_t idx = (size_t)c * (NH * TT) + i;
    float Mc = Mp[idx], Lc = Lp[idx], sac = sap[idx], scc = scp[idx];
    float nM = fmaxf(M, Mc);
    float s1 = __expf(M - nM), s2 = __expf(Mc - nM);
    L = L * s1 + Lc * s2;
    sa = sa * s1 + sac * s2;
    sc = sc * s1 + scc * s2;
    M = nM;
  }
  float logL = __logf(L);
  Mst[i] = M; Lst[i] = logL;
  entraw[i] = (M + logL - sa / L) * (1.0f / LNT);
  int t = i & (TT - 1);
  dep[i] = (1.f - sc / L) / divsum[t];
}

__global__ __launch_bounds__(256) void k_entnorm(const float* __restrict__ entraw,
                                                 float* __restrict__ ent) {
  int h = blockIdx.x;
  float s = 0.f;
  for (int t = threadIdx.x; t < TT; t += 256) s += fabsf(entraw[h * TT + t]);
  s = blockReduceSum256(s);
  float inv = 1.f / fmaxf(s, 1e-12f);
  for (int t = threadIdx.x; t < TT; t += 256) ent[h * TT + t] = entraw[h * TT + t] * inv;
}

// V'^T[h][e][s] = bf16( V[s][h*DH+e] * (1+dep[h][s]) )
__global__ __launch_bounds__(256) void k_vprime(const ushort_t* __restrict__ Vbf,
                                                const float* __restrict__ dep,
                                                ushort_t* __restrict__ VT) {
  int h = blockIdx.y, s0 = blockIdx.x * 64;
  __shared__ float tile[64][130];
  int tid = threadIdx.x;
  for (int idx = tid; idx < 64 * 64; idx += 256) {
    int r = idx >> 6, c2 = (idx & 63) * 2;
    unsigned u = *(const unsigned*)&Vbf[(size_t)(s0 + r) * 1024 + h * DH + c2];
    tile[r][c2] = bf2f((ushort_t)(u & 0xffffu));
    tile[r][c2 + 1] = bf2f((ushort_t)(u >> 16));
  }
  __syncthreads();
  int e = tid >> 1, sh = (tid & 1) * 32;
  #pragma unroll
  for (int g = 0; g < 8; g++) {
    int sb = sh + g * 4;
    float v0 = tile[sb + 0][e] * (1.f + dep[h * TT + s0 + sb + 0]);
    float v1 = tile[sb + 1][e] * (1.f + dep[h * TT + s0 + sb + 1]);
    float v2 = tile[sb + 2][e] * (1.f + dep[h * TT + s0 + sb + 2]);
    float v3 = tile[sb + 3][e] * (1.f + dep[h * TT + s0 + sb + 3]);
    uint2 wv;
    wv.x = (unsigned)f2bf(v0) | ((unsigned)f2bf(v1) << 16);
    wv.y = (unsigned)f2bf(v2) | ((unsigned)f2bf(v3) << 16);
    *(uint2*)&VT[(size_t)(h * DH + e) * TT + s0 + sb] = wv;
  }
}

// ---- phase 2: fp16 QK^T, LDS-staged K & V', 8-wave blocks, z=4 partial-y ----
__global__ __launch_bounds__(512, 4) void k_phase2m(
    const ushort_t* __restrict__ Qf, const ushort_t* __restrict__ Kf,
    const ushort_t* __restrict__ APh, const ushort_t* __restrict__ VT,
    const float* __restrict__ Mst, const float* __restrict__ Lst,
    const float* __restrict__ dep,
    float* __restrict__ yp0, float* __restrict__ yp1,
    float* __restrict__ yp2, float* __restrict__ yp3,
    float* __restrict__ out2) {
  int h = blockIdx.y, z = blockIdx.z;
  int tid = threadIdx.x, lane = tid & 63, w = tid >> 6;
  int l15 = lane & 15, lg = lane >> 4;
  int rowbase = blockIdx.x * 128 + w * 16;
  bool last = (h == NH - 1);
  float* yp = (z == 0) ? yp0 : (z == 1) ? yp1 : (z == 2) ? yp2 : yp3;

  __shared__ __align__(16) ushort_t Ks[64 * 128];   // fp16 K tile
  __shared__ __align__(16) ushort_t Vs[128 * 64];   // bf16 V' tile [e][s]
  __shared__ __align__(16) ushort_t Pst[8][16][72]; // bf16 P, per wave

  f16x8 q[4];
  {
    const ushort_t* qp = Qf + (size_t)(rowbase + l15) * 1024 + h * DH + lg * 8;
    #pragma unroll
    for (int kc = 0; kc < 4; kc++) q[kc] = ld8f(qp + kc * 32);
  }
  float ml[4];
  #pragma unroll
  for (int r = 0; r < 4; r++) {
    int t = rowbase + lg * 4 + r;
    ml[r] = Mst[h * TT + t] + Lst[h * TT + t];
  }
  int n0 = w * 128 + lane;
  int sr0 = n0 >> 4, su0 = n0 & 15, sr1 = sr0 + 4;
  int kwo0 = sr0 * 128 + ((su0 ^ (sr0 & 7)) * 8);
  int kwo1 = sr1 * 128 + ((su0 ^ (sr1 & 7)) * 8);
  const ushort_t* kg0 = Kf + (size_t)sr0 * 1024 + h * DH + su0 * 8;
  const ushort_t* kg1 = Kf + (size_t)sr1 * 1024 + h * DH + su0 * 8;
  int ve0 = n0 >> 3, vu0 = n0 & 7;
  int vwo0 = ve0 * 64 + ((vu0 ^ (ve0 & 7)) * 8);
  int vwo1 = vwo0 + 512;
  const ushort_t* vg0 = VT + (size_t)(h * DH + ve0) * TT + vu0 * 8;
  const ushort_t* vg1 = vg0 + (size_t)8 * TT;

  f32x4 yacc[8];
  #pragma unroll
  for (int et = 0; et < 8; et++) yacc[et] = (f32x4)0.f;

  for (int s0 = z * 512; s0 < z * 512 + 512; s0 += 64) {
    uintx4 ka = *(const uintx4*)(kg0 + (size_t)s0 * 1024);
    uintx4 kb = *(const uintx4*)(kg1 + (size_t)s0 * 1024);
    uintx4 va = *(const uintx4*)(vg0 + s0);
    uintx4 vb = *(const uintx4*)(vg1 + s0);
    __syncthreads();
    *(uintx4*)(Ks + kwo0) = ka;
    *(uintx4*)(Ks + kwo1) = kb;
    *(uintx4*)(Vs + vwo0) = va;
    *(uintx4*)(Vs + vwo1) = vb;
    __syncthreads();
    f32x4 acc[4];
    #pragma unroll
    for (int ct = 0; ct < 4; ct++) acc[ct] = (f32x4)0.f;
    #pragma unroll
    for (int ct = 0; ct < 4; ct++) {
      int row = ct * 16 + l15, rb = row * 128, rs = row & 7;
      #pragma unroll
      for (int kc = 0; kc < 4; kc++) {
        f16x8 b = ld8f(Ks + rb + (((kc * 4 + lg) ^ rs) * 8));
        acc[ct] = MFMA16F(q[kc], b, acc[ct]);
      }
    }
    float dv[4];
    if (last) {
      #pragma unroll
      for (int ct = 0; ct < 4; ct++) dv[ct] = dep[(NH - 1) * TT + s0 + ct * 16 + l15];
    }
    #pragma unroll
    for (int ct = 0; ct < 4; ct++) {
      #pragma unroll
      for (int r = 0; r < 4; r++) {
        int t = rowbase + lg * 4 + r;
        float e = acc[ct][r] + h2f(APh[(size_t)t * TT + s0 + ct * 16 + l15]);
        float a = __expf(e - ml[r]);
        Pst[w][lg * 4 + r][ct * 16 + l15] = f2bf(a);
        if (last) out2[(size_t)t * TT + s0 + ct * 16 + l15] = a * (1.f + dv[ct]);
      }
    }
    asm volatile("" ::: "memory");   // wave-internal: P writes before P reads
    #pragma unroll
    for (int c = 0; c < 2; c++) {
      bf16x8 ap = *(const bf16x8*)&Pst[w][l15][c * 32 + lg * 8];
      #pragma unroll
      for (int et = 0; et < 8; et++) {
        int e = et * 16 + l15;
        bf16x8 bv = ld8(Vs + e * 64 + (((c * 4 + lg) ^ (l15 & 7)) * 8));
        yacc[et] = MFMA16(ap, bv, yacc[et]);
      }
    }
    asm volatile("" ::: "memory");
  }
  #pragma unroll
  for (int et = 0; et < 8; et++)
    #pragma unroll
    for (int r = 0; r < 4; r++)
      yp[((size_t)h * TT + rowbase + lg * 4 + r) * DH + et * 16 + l15] = yacc[et][r];
}

// y_s = [sum(yp0..3) | ent | dep] @ W2^T -> ycat fp16
__global__ __launch_bounds__(256) void k_ys(const float* __restrict__ yp0,
                                            const float* __restrict__ yp1,
                                            const float* __restrict__ yp2,
                                            const float* __restrict__ yp3,
                                            const float* __restrict__ ent,
                                            const float* __restrict__ dep,
                                            const float* __restrict__ W2,
                                            ushort_t* __restrict__ ycf) {
  int h = blockIdx.x, t0 = blockIdx.y * 2;
  int tid = threadIdx.x;
  __shared__ float yls[2][128];
  {
    int rr = tid >> 7, cc = tid & 127;
    size_t idx = ((size_t)h * TT + t0 + rr) * DH + cc;
    yls[rr][cc] = (yp0[idx] + yp1[idx]) + (yp2[idx] + yp3[idx]);
  }
  __syncthreads();
  int trow = tid >> 7, o = tid & 127;
  int t = t0 + trow;
  float et = ent[h * TT + t], dp = dep[h * TT + t];
  float s = 0.f;
  #pragma unroll 4
  for (int f = 0; f < DH; f++) s += yls[trow][f] * W2[o * 130 + f];
  s += et * W2[o * 130 + 128] + dp * W2[o * 130 + 129];
  ycf[(size_t)t * 1024 + h * DH + o] = f2h(s);
}

extern "C" void kernel_launch(void* const* d_in, const int* in_sizes, int n_in,
                              void* d_out, int out_size, void* d_ws, size_t ws_size,
                              hipStream_t stream) {
  const float* x  = (const float*)d_in[0];
  const float* Wq = (const float*)d_in[1];
  const float* Wk = (const float*)d_in[2];
  const float* Wv = (const float*)d_in[3];
  const float* W2 = (const float*)d_in[4];
  const float* Wo = (const float*)d_in[5];
  float* out  = (float*)d_out;                  // [T,1024]
  float* out2 = out + (size_t)TT * 1024;        // att_win[-1] [T,T]
  float* ws = (float*)d_ws;

  ushort_t* xf   = (ushort_t*)(ws + F_XF);
  ushort_t* Uf   = (ushort_t*)(ws + F_UF);
  ushort_t* Qf   = (ushort_t*)(ws + F_QF);
  ushort_t* Kf   = (ushort_t*)(ws + F_KF);
  ushort_t* Vbf  = (ushort_t*)(ws + F_VBF);
  ushort_t* VT   = (ushort_t*)(ws + F_VT);
  ushort_t* ycf  = (ushort_t*)(ws + F_YCF);
  ushort_t* Wcat = (ushort_t*)(ws + F_WCAT);
  ushort_t* Wof  = (ushort_t*)(ws + F_WOF);
  ushort_t* APh  = (ushort_t*)(ws + F_APH);
  float*    Cm   = ws + F_C;
  float* divsum = ws + F_DIVS;
  float* Mst    = ws + F_MST;
  float* Lst    = ws + F_LST;
  float* entraw = ws + F_ENTR;
  float* ent    = ws + F_ENT;
  float* dep    = ws + F_DEP;
  float* Mp     = ws + F_MP;
  float* Lp     = ws + F_LP;
  float* sap    = ws + F_SAP;
  float* scp    = ws + F_SCP;
  float* yp0    = ws + F_YP0;
  float* yp1    = ws + F_YP1;
  float* yp2    = ws + F_YP2;
  float* yp3    = ws + F_YP3;

  k_tof16<<<2048, 256, 0, stream>>>(x, xf, 524288);
  k_rownorm_f16<<<TT, 256, 0, stream>>>(x, Uf);
  k_tof16<<<1024, 256, 0, stream>>>(Wq, Wcat, 262144);
  k_tof16<<<1024, 256, 0, stream>>>(Wk, Wcat + 1048576, 262144);
  k_tof16<<<1024, 256, 0, stream>>>(Wv, Wcat + 2097152, 262144);
  k_tof16<<<1024, 256, 0, stream>>>(Wo, Wof, 262144);

  k_gemm<0><<<dim3(16, 16), 256, 0, stream>>>(Uf, Uf, Cm, nullptr,
                                              nullptr, nullptr, nullptr, TT, TT, 1024);
  k_gemm<3><<<dim3(24, 16), 256, 0, stream>>>(xf, Wcat, nullptr, nullptr,
                                              Qf, Kf, Vbf, TT, 3072, 1024);

  k_divsum<<<TT, 256, 0, stream>>>(Cm, divsum);
  k_aph<<<TT, 256, 0, stream>>>(APh);

  k_phase1m<<<dim3(16, NH, 4), 512, 0, stream>>>(Qf, Kf, APh, Cm, Mp, Lp, sap, scp);
  k_combine<<<64, 256, 0, stream>>>(Mp, Lp, sap, scp, divsum, Mst, Lst, entraw, dep);
  k_entnorm<<<NH, 256, 0, stream>>>(entraw, ent);
  k_vprime<<<dim3(32, NH), 256, 0, stream>>>(Vbf, dep, VT);
  k_phase2m<<<dim3(16, NH, 4), 512, 0, stream>>>(Qf, Kf, APh, VT, Mst, Lst, dep,
                                                 yp0, yp1, yp2, yp3, out2);
  k_ys<<<dim3(NH, TT / 2), 256, 0, stream>>>(yp0, yp1, yp2, yp3, ent, dep, W2, ycf);
  k_gemm<0><<<dim3(8, 16), 256, 0, stream>>>(ycf, Wof, out, nullptr,
                                             nullptr, nullptr, nullptr, TT, 1024, 1024);
}

// Round 6
// 203.859 us; speedup vs baseline: 9.3807x; 1.2645x over previous
//
#include <hip/hip_runtime.h>
#include <math.h>

#define TT  2048
#define NH  8
#define DH  128
#define LNT 7.6246189861593985f   // ln(2048)

typedef unsigned short ushort_t;
typedef __bf16 bf16x8 __attribute__((ext_vector_type(8)));
typedef _Float16 f16x8 __attribute__((ext_vector_type(8)));
typedef float f32x4 __attribute__((ext_vector_type(4)));
typedef unsigned int uintx4 __attribute__((ext_vector_type(4)));

#define MFMA16(a, b, c)  __builtin_amdgcn_mfma_f32_16x16x32_bf16(a, b, c, 0, 0, 0)
#define MFMA16F(a, b, c) __builtin_amdgcn_mfma_f32_16x16x32_f16(a, b, c, 0, 0, 0)

__device__ __forceinline__ bf16x8 ld8(const ushort_t* p) {
  uintx4 v = *(const uintx4*)p;
  return __builtin_bit_cast(bf16x8, v);
}
__device__ __forceinline__ f16x8 ld8f(const ushort_t* p) {
  uintx4 v = *(const uintx4*)p;
  return __builtin_bit_cast(f16x8, v);
}
__device__ __forceinline__ ushort_t f2bf(float x) {
  unsigned u = __float_as_uint(x);
  return (ushort_t)((u + 0x7fffu + ((u >> 16) & 1u)) >> 16);
}
__device__ __forceinline__ float bf2f(ushort_t b) {
  return __uint_as_float(((unsigned)b) << 16);
}
__device__ __forceinline__ ushort_t f2h(float x) {
  return __builtin_bit_cast(ushort_t, (_Float16)x);
}
__device__ __forceinline__ float h2f(ushort_t b) {
  return (float)__builtin_bit_cast(_Float16, b);
}

// ---- workspace layout (float offsets). Total 16,777,216 floats = 64MB (proven safe).
enum : size_t {
  F_XF   = 0u,          // x fp16 [1M] -> yp0 fp32 [0,2M) in phase2
  F_UF   = 1048576u,    // U fp16 [1M]
  F_QF   = 2097152u,    // Q fp16 -> ysh fp16 [8][2048][192] (1.5M floats) after phase2
  F_KF   = 3145728u,    // K fp16 (ysh tail overlays; Kf dead after phase2)
  F_VBF  = 4194304u,    // V bf16
  F_VT   = 5242880u,    // V'^T bf16 [H*DH, T]
  F_YCF  = 6291456u,    // ycat fp16
  F_WCAT = 7340032u,    // Wq|Wk|Wv fp16 [3072,1024] = 1.5M -> yp3 after QKV gemm
  F_WOF  = 9437184u,    // Wout fp16 [0.5M], kept to the end
  F_DIVS = 9961472u,
  F_MST  = 9963520u,
  F_LST  = 9979904u,
  F_ENTR = 9996288u,
  F_ENT  = 10012672u,
  F_DEP  = 10029056u,
  F_MP   = 10045440u,   // [4][16384] partial stats
  F_LP   = 10110976u,
  F_SAP  = 10176512u,
  F_SCP  = 10242048u,   // ends 10307584
  F_W2F  = 10307584u,   // W2 fp16 padded [128][192] = 12288 floats, ends 10319872 < 10485760
  F_APH  = 10485760u,   // AP fp16 [T,T] = 2M floats
  F_C    = 12582912u,   // C fp32 [4M] -> yp1/yp2 in phase2
  F_YP0  = 0u,
  F_YP1  = 12582912u,
  F_YP2  = 14680064u,
  F_YP3  = 7340032u,
  F_YSH  = 2097152u,    // ysh overlay (Qf/Kf dead)
};

__device__ __forceinline__ float blockReduceSum256(float v) {
  __shared__ float sh[4];
  #pragma unroll
  for (int m = 1; m < 64; m <<= 1) v += __shfl_xor(v, m, 64);
  if ((threadIdx.x & 63) == 0) sh[threadIdx.x >> 6] = v;
  __syncthreads();
  float r = sh[0] + sh[1] + sh[2] + sh[3];
  __syncthreads();
  return r;
}

__global__ __launch_bounds__(256) void k_rownorm_f16(const float* __restrict__ x,
                                                     ushort_t* __restrict__ Uf) {
  int t = blockIdx.x;
  const float* xr = x + (size_t)t * 1024;
  float ss = 0.f;
  for (int d = threadIdx.x; d < 1024; d += 256) { float v = xr[d]; ss += v * v; }
  ss = blockReduceSum256(ss);
  float inv = 1.f / fmaxf(sqrtf(ss), 1e-12f);
  for (int d = threadIdx.x; d < 1024; d += 256)
    Uf[(size_t)t * 1024 + d] = f2h(xr[d] * inv);
}

__global__ __launch_bounds__(256) void k_tof16(const float* __restrict__ s,
                                               ushort_t* __restrict__ d, int n4) {
  int i = blockIdx.x * 256 + threadIdx.x;
  if (i >= n4) return;
  float4 v = ((const float4*)s)[i];
  uint2 w;
  w.x = (unsigned)f2h(v.x) | ((unsigned)f2h(v.y) << 16);
  w.y = (unsigned)f2h(v.z) | ((unsigned)f2h(v.w) << 16);
  ((uint2*)d)[i] = w;
}

// W2 [128][130] f32 -> [128][192] fp16, zero-padded
__global__ __launch_bounds__(256) void k_w2pad(const float* __restrict__ W2,
                                               ushort_t* __restrict__ W2f) {
  int idx = blockIdx.x * 256 + threadIdx.x;
  if (idx >= 128 * 192) return;
  int o = idx / 192, c = idx % 192;
  W2f[idx] = (c < 130) ? f2h(W2[o * 130 + c]) : (ushort_t)0;
}

// ---- m97-style NT GEMM: D[M,N] = A[M,K] * B[N,K]^T, fp16 in, 128x128 tile, BK=64.
// MODE: 0 f32 out; 1 fp16 out; 2 bf16 out; 3 QKV split; 4 ys remap (h,t,o)->ycat[t][h*128+o].
template <int MODE>
__global__ __launch_bounds__(256) void k_gemm(
    const ushort_t* __restrict__ A, const ushort_t* __restrict__ B,
    float* __restrict__ Df, ushort_t* __restrict__ Dh,
    ushort_t* __restrict__ Dq, ushort_t* __restrict__ Dk, ushort_t* __restrict__ Dv,
    int M, int N, int K) {
  __shared__ __align__(16) ushort_t As[128 * 64];
  __shared__ __align__(16) ushort_t Bs[128 * 64];
  int tid = threadIdx.x, lane = tid & 63, w = tid >> 6;
  int l15 = lane & 15, lg = lane >> 4;
  int wr = w >> 1, wc = w & 1;
  int m0 = blockIdx.y * 128, n0 = blockIdx.x * 128;

  const ushort_t* ga[4];
  const ushort_t* gb[4];
  ushort_t* la[4];
  ushort_t* lb[4];
  #pragma unroll
  for (int j = 0; j < 4; j++) {
    int u = (4 * w + j) * 64 + lane;
    int row = u >> 3;
    int kc8 = (u & 7) ^ (row & 7);
    ga[j] = A + (size_t)(m0 + row) * K + kc8 * 8;
    gb[j] = B + (size_t)(n0 + row) * K + kc8 * 8;
    la[j] = As + (4 * w + j) * 512;
    lb[j] = Bs + (4 * w + j) * 512;
  }

  f32x4 acc[4][4];
  #pragma unroll
  for (int i = 0; i < 4; i++)
    #pragma unroll
    for (int ct = 0; ct < 4; ct++) acc[i][ct] = (f32x4)0.f;

  for (int k0 = 0; k0 < K; k0 += 64) {
    __syncthreads();
    #pragma unroll
    for (int j = 0; j < 4; j++) {
      __builtin_amdgcn_global_load_lds(
          (const __attribute__((address_space(1))) void*)(ga[j] + k0),
          (__attribute__((address_space(3))) void*)la[j], 16, 0, 0);
      __builtin_amdgcn_global_load_lds(
          (const __attribute__((address_space(1))) void*)(gb[j] + k0),
          (__attribute__((address_space(3))) void*)lb[j], 16, 0, 0);
    }
    __syncthreads();
    #pragma unroll
    for (int kc = 0; kc < 2; kc++) {
      f16x8 af[4], bfr[4];
      #pragma unroll
      for (int i = 0; i < 4; i++) {
        int ra = wr * 64 + i * 16 + l15;
        af[i] = ld8f(As + (ra * 8 + ((kc * 4 + lg) ^ (ra & 7))) * 8);
        int rb = wc * 64 + i * 16 + l15;
        bfr[i] = ld8f(Bs + (rb * 8 + ((kc * 4 + lg) ^ (rb & 7))) * 8);
      }
      #pragma unroll
      for (int i = 0; i < 4; i++)
        #pragma unroll
        for (int ct = 0; ct < 4; ct++)
          acc[i][ct] = MFMA16F(af[i], bfr[ct], acc[i][ct]);
    }
  }
  #pragma unroll
  for (int i = 0; i < 4; i++) {
    #pragma unroll
    for (int ct = 0; ct < 4; ct++) {
      #pragma unroll
      for (int r = 0; r < 4; r++) {
        size_t mm = m0 + wr * 64 + i * 16 + lg * 4 + r;
        size_t nn = n0 + wc * 64 + ct * 16 + l15;
        float v = acc[i][ct][r];
        if (MODE == 0) Df[mm * N + nn] = v;
        if (MODE == 1) Dh[mm * N + nn] = f2h(v);
        if (MODE == 2) Dh[mm * N + nn] = f2bf(v);
        if (MODE == 3) {
          if (nn < 1024) Dq[mm * 1024 + nn] = f2h(v);
          else if (nn < 2048) Dk[mm * 1024 + nn - 1024] = f2h(v);
          else Dv[mm * 1024 + nn - 2048] = f2bf(v);
        }
        if (MODE == 4) {
          size_t hh = mm >> 11, tt2 = mm & 2047;
          Dh[tt2 * 1024 + hh * 128 + nn] = f2h(v);
        }
      }
    }
  }
}

__global__ __launch_bounds__(256) void k_divsum(const float* __restrict__ C,
                                                float* __restrict__ divsum) {
  int t = blockIdx.x;
  float s = 0.f;
  for (int j = threadIdx.x; j < TT; j += 256) s += C[(size_t)t * TT + j];
  s = blockReduceSum256(s);
  if (threadIdx.x == 0) divsum[t] = (float)TT - s;
}

__global__ __launch_bounds__(256) void k_aph(ushort_t* __restrict__ APh) {
  int t = blockIdx.x;
  for (int j = threadIdx.x; j < TT; j += 256) {
    int i = j >> 1;
    float invf = __expf((float)i * -0.017988946039016016f); // -ln(1e4)/512
    float ang = (float)t * invf;
    APh[(size_t)t * TT + j] = f2h((j & 1) ? cosf(ang) : sinf(ang));
  }
}

// ---- phase 1: fp16 QK^T, 8-wave blocks, K tile LDS-staged (XOR-swizzled) ----
__global__ __launch_bounds__(512, 4) void k_phase1m(
    const ushort_t* __restrict__ Qf, const ushort_t* __restrict__ Kf,
    const ushort_t* __restrict__ APh, const float* __restrict__ Cm,
    float* __restrict__ Mp, float* __restrict__ Lp,
    float* __restrict__ sap, float* __restrict__ scp) {
  int h = blockIdx.y, z = blockIdx.z;
  int tid = threadIdx.x, lane = tid & 63, w = tid >> 6;
  int l15 = lane & 15, lg = lane >> 4;
  int rowbase = blockIdx.x * 128 + w * 16;
  __shared__ __align__(16) ushort_t Ks[64 * 128];   // fp16, unit-swizzled

  f16x8 q[4];
  {
    const ushort_t* qp = Qf + (size_t)(rowbase + l15) * 1024 + h * DH + lg * 8;
    #pragma unroll
    for (int kc = 0; kc < 4; kc++) q[kc] = ld8f(qp + kc * 32);
  }
  int n0 = w * 128 + lane;
  int sr0 = n0 >> 4, su0 = n0 & 15, sr1 = sr0 + 4;
  int wo0 = sr0 * 128 + ((su0 ^ (sr0 & 7)) * 8);
  int wo1 = sr1 * 128 + ((su0 ^ (sr1 & 7)) * 8);
  const ushort_t* kg0 = Kf + (size_t)sr0 * 1024 + h * DH + su0 * 8;
  const ushort_t* kg1 = Kf + (size_t)sr1 * 1024 + h * DH + su0 * 8;

  float Mv[4], Lv[4], sae[4], snc[4];
  #pragma unroll
  for (int r = 0; r < 4; r++) { Mv[r] = -1e30f; Lv[r] = 0.f; sae[r] = 0.f; snc[r] = 0.f; }

  for (int s0 = z * 512; s0 < z * 512 + 512; s0 += 64) {
    uintx4 ka = *(const uintx4*)(kg0 + (size_t)s0 * 1024);
    uintx4 kb = *(const uintx4*)(kg1 + (size_t)s0 * 1024);
    __syncthreads();
    *(uintx4*)(Ks + wo0) = ka;
    *(uintx4*)(Ks + wo1) = kb;
    __syncthreads();
    f32x4 acc[4];
    #pragma unroll
    for (int ct = 0; ct < 4; ct++) acc[ct] = (f32x4)0.f;
    #pragma unroll
    for (int ct = 0; ct < 4; ct++) {
      int row = ct * 16 + l15, rb = row * 128, rs = row & 7;
      #pragma unroll
      for (int kc = 0; kc < 4; kc++) {
        f16x8 b = ld8f(Ks + rb + (((kc * 4 + lg) ^ rs) * 8));
        acc[ct] = MFMA16F(q[kc], b, acc[ct]);
      }
    }
    #pragma unroll
    for (int r = 0; r < 4; r++) {
      int t = rowbase + lg * 4 + r;
      float e0 = acc[0][r] + h2f(APh[(size_t)t * TT + s0 +  0 + l15]);
      float e1 = acc[1][r] + h2f(APh[(size_t)t * TT + s0 + 16 + l15]);
      float e2 = acc[2][r] + h2f(APh[(size_t)t * TT + s0 + 32 + l15]);
      float e3 = acc[3][r] + h2f(APh[(size_t)t * TT + s0 + 48 + l15]);
      float c0 = Cm[(size_t)t * TT + s0 +  0 + l15];
      float c1 = Cm[(size_t)t * TT + s0 + 16 + l15];
      float c2 = Cm[(size_t)t * TT + s0 + 32 + l15];
      float c3 = Cm[(size_t)t * TT + s0 + 48 + l15];
      float m2 = fmaxf(fmaxf(e0, e1), fmaxf(e2, e3));
      float newM = fmaxf(Mv[r], m2);
      float rsc = __expf(Mv[r] - newM);
      float p0 = __expf(e0 - newM), p1 = __expf(e1 - newM);
      float p2 = __expf(e2 - newM), p3 = __expf(e3 - newM);
      Lv[r]  = Lv[r]  * rsc + (p0 + p1) + (p2 + p3);
      sae[r] = sae[r] * rsc + (p0 * e0 + p1 * e1) + (p2 * e2 + p3 * e3);
      snc[r] = snc[r] * rsc + (p0 * c0 + p1 * c1) + (p2 * c2 + p3 * c3);
      Mv[r] = newM;
    }
  }
  #pragma unroll
  for (int r = 0; r < 4; r++) {
    #pragma unroll
    for (int m = 1; m < 16; m <<= 1) {
      float Mo = __shfl_xor(Mv[r], m, 64);
      float Lo = __shfl_xor(Lv[r], m, 64);
      float so = __shfl_xor(sae[r], m, 64);
      float co = __shfl_xor(snc[r], m, 64);
      float nM = fmaxf(Mv[r], Mo);
      float s1 = __expf(Mv[r] - nM), s2 = __expf(Mo - nM);
      Lv[r]  = Lv[r]  * s1 + Lo * s2;
      sae[r] = sae[r] * s1 + so * s2;
      snc[r] = snc[r] * s1 + co * s2;
      Mv[r] = nM;
    }
  }
  if (l15 == 0) {
    #pragma unroll
    for (int r = 0; r < 4; r++) {
      int t = rowbase + lg * 4 + r;
      size_t idx = (size_t)z * (NH * TT) + h * TT + t;
      Mp[idx] = Mv[r]; Lp[idx] = Lv[r]; sap[idx] = sae[r]; scp[idx] = snc[r];
    }
  }
}

__global__ __launch_bounds__(256) void k_combine(
    const float* __restrict__ Mp, const float* __restrict__ Lp,
    const float* __restrict__ sap, const float* __restrict__ scp,
    const float* __restrict__ divsum,
    float* __restrict__ Mst, float* __restrict__ Lst,
    float* __restrict__ entraw, float* __restrict__ dep) {
  int i = blockIdx.x * 256 + threadIdx.x;
  if (i >= NH * TT) return;
  float M = -1e30f, L = 0.f, sa = 0.f, sc = 0.f;
  #pragma unroll
  for (int c = 0; c < 4; c++) {
    size_t idx = (size_t)c * (NH * TT) + i;
    float Mc = Mp[idx], Lc = Lp[idx], sac = sap[idx], scc = scp[idx];
    float nM = fmaxf(M, Mc);
    float s1 = __expf(M - nM), s2 = __expf(Mc - nM);
    L = L * s1 + Lc * s2;
    sa = sa * s1 + sac * s2;
    sc = sc * s1 + scc * s2;
    M = nM;
  }
  float logL = __logf(L);
  Mst[i] = M; Lst[i] = logL;
  entraw[i] = (M + logL - sa / L) * (1.0f / LNT);
  int t = i & (TT - 1);
  dep[i] = (1.f - sc / L) / divsum[t];
}

__global__ __launch_bounds__(256) void k_entnorm(const float* __restrict__ entraw,
                                                 float* __restrict__ ent) {
  int h = blockIdx.x;
  float s = 0.f;
  for (int t = threadIdx.x; t < TT; t += 256) s += fabsf(entraw[h * TT + t]);
  s = blockReduceSum256(s);
  float inv = 1.f / fmaxf(s, 1e-12f);
  for (int t = threadIdx.x; t < TT; t += 256) ent[h * TT + t] = entraw[h * TT + t] * inv;
}

// V'^T[h][e][s] = bf16( V[s][h*DH+e] * (1+dep[h][s]) )
__global__ __launch_bounds__(256) void k_vprime(const ushort_t* __restrict__ Vbf,
                                                const float* __restrict__ dep,
                                                ushort_t* __restrict__ VT) {
  int h = blockIdx.y, s0 = blockIdx.x * 64;
  __shared__ float tile[64][130];
  int tid = threadIdx.x;
  for (int idx = tid; idx < 64 * 64; idx += 256) {
    int r = idx >> 6, c2 = (idx & 63) * 2;
    unsigned u = *(const unsigned*)&Vbf[(size_t)(s0 + r) * 1024 + h * DH + c2];
    tile[r][c2] = bf2f((ushort_t)(u & 0xffffu));
    tile[r][c2 + 1] = bf2f((ushort_t)(u >> 16));
  }
  __syncthreads();
  int e = tid >> 1, sh = (tid & 1) * 32;
  #pragma unroll
  for (int g = 0; g < 8; g++) {
    int sb = sh + g * 4;
    float v0 = tile[sb + 0][e] * (1.f + dep[h * TT + s0 + sb + 0]);
    float v1 = tile[sb + 1][e] * (1.f + dep[h * TT + s0 + sb + 1]);
    float v2 = tile[sb + 2][e] * (1.f + dep[h * TT + s0 + sb + 2]);
    float v3 = tile[sb + 3][e] * (1.f + dep[h * TT + s0 + sb + 3]);
    uint2 wv;
    wv.x = (unsigned)f2bf(v0) | ((unsigned)f2bf(v1) << 16);
    wv.y = (unsigned)f2bf(v2) | ((unsigned)f2bf(v3) << 16);
    *(uint2*)&VT[(size_t)(h * DH + e) * TT + s0 + sb] = wv;
  }
}

// ---- phase 2: fp16 QK^T, LDS-staged K & V', 8-wave blocks, z=4 partial-y ----
__global__ __launch_bounds__(512, 4) void k_phase2m(
    const ushort_t* __restrict__ Qf, const ushort_t* __restrict__ Kf,
    const ushort_t* __restrict__ APh, const ushort_t* __restrict__ VT,
    const float* __restrict__ Mst, const float* __restrict__ Lst,
    const float* __restrict__ dep,
    float* __restrict__ yp0, float* __restrict__ yp1,
    float* __restrict__ yp2, float* __restrict__ yp3,
    float* __restrict__ out2) {
  int h = blockIdx.y, z = blockIdx.z;
  int tid = threadIdx.x, lane = tid & 63, w = tid >> 6;
  int l15 = lane & 15, lg = lane >> 4;
  int rowbase = blockIdx.x * 128 + w * 16;
  bool last = (h == NH - 1);
  float* yp = (z == 0) ? yp0 : (z == 1) ? yp1 : (z == 2) ? yp2 : yp3;

  __shared__ __align__(16) ushort_t Ks[64 * 128];   // fp16 K tile
  __shared__ __align__(16) ushort_t Vs[128 * 64];   // bf16 V' tile [e][s]
  __shared__ __align__(16) ushort_t Pst[8][16][72]; // bf16 P, per wave

  f16x8 q[4];
  {
    const ushort_t* qp = Qf + (size_t)(rowbase + l15) * 1024 + h * DH + lg * 8;
    #pragma unroll
    for (int kc = 0; kc < 4; kc++) q[kc] = ld8f(qp + kc * 32);
  }
  float ml[4];
  #pragma unroll
  for (int r = 0; r < 4; r++) {
    int t = rowbase + lg * 4 + r;
    ml[r] = Mst[h * TT + t] + Lst[h * TT + t];
  }
  int n0 = w * 128 + lane;
  int sr0 = n0 >> 4, su0 = n0 & 15, sr1 = sr0 + 4;
  int kwo0 = sr0 * 128 + ((su0 ^ (sr0 & 7)) * 8);
  int kwo1 = sr1 * 128 + ((su0 ^ (sr1 & 7)) * 8);
  const ushort_t* kg0 = Kf + (size_t)sr0 * 1024 + h * DH + su0 * 8;
  const ushort_t* kg1 = Kf + (size_t)sr1 * 1024 + h * DH + su0 * 8;
  int ve0 = n0 >> 3, vu0 = n0 & 7;
  int vwo0 = ve0 * 64 + ((vu0 ^ (ve0 & 7)) * 8);
  int vwo1 = vwo0 + 512;
  const ushort_t* vg0 = VT + (size_t)(h * DH + ve0) * TT + vu0 * 8;
  const ushort_t* vg1 = vg0 + (size_t)8 * TT;

  f32x4 yacc[8];
  #pragma unroll
  for (int et = 0; et < 8; et++) yacc[et] = (f32x4)0.f;

  for (int s0 = z * 512; s0 < z * 512 + 512; s0 += 64) {
    uintx4 ka = *(const uintx4*)(kg0 + (size_t)s0 * 1024);
    uintx4 kb = *(const uintx4*)(kg1 + (size_t)s0 * 1024);
    uintx4 va = *(const uintx4*)(vg0 + s0);
    uintx4 vb = *(const uintx4*)(vg1 + s0);
    __syncthreads();
    *(uintx4*)(Ks + kwo0) = ka;
    *(uintx4*)(Ks + kwo1) = kb;
    *(uintx4*)(Vs + vwo0) = va;
    *(uintx4*)(Vs + vwo1) = vb;
    __syncthreads();
    f32x4 acc[4];
    #pragma unroll
    for (int ct = 0; ct < 4; ct++) acc[ct] = (f32x4)0.f;
    #pragma unroll
    for (int ct = 0; ct < 4; ct++) {
      int row = ct * 16 + l15, rb = row * 128, rs = row & 7;
      #pragma unroll
      for (int kc = 0; kc < 4; kc++) {
        f16x8 b = ld8f(Ks + rb + (((kc * 4 + lg) ^ rs) * 8));
        acc[ct] = MFMA16F(q[kc], b, acc[ct]);
      }
    }
    float dv[4];
    if (last) {
      #pragma unroll
      for (int ct = 0; ct < 4; ct++) dv[ct] = dep[(NH - 1) * TT + s0 + ct * 16 + l15];
    }
    #pragma unroll
    for (int ct = 0; ct < 4; ct++) {
      #pragma unroll
      for (int r = 0; r < 4; r++) {
        int t = rowbase + lg * 4 + r;
        float e = acc[ct][r] + h2f(APh[(size_t)t * TT + s0 + ct * 16 + l15]);
        float a = __expf(e - ml[r]);
        Pst[w][lg * 4 + r][ct * 16 + l15] = f2bf(a);
        if (last) out2[(size_t)t * TT + s0 + ct * 16 + l15] = a * (1.f + dv[ct]);
      }
    }
    asm volatile("" ::: "memory");   // wave-internal: P writes before P reads
    #pragma unroll
    for (int c = 0; c < 2; c++) {
      bf16x8 ap = *(const bf16x8*)&Pst[w][l15][c * 32 + lg * 8];
      #pragma unroll
      for (int et = 0; et < 8; et++) {
        int e = et * 16 + l15;
        bf16x8 bv = ld8(Vs + e * 64 + (((c * 4 + lg) ^ (l15 & 7)) * 8));
        yacc[et] = MFMA16(ap, bv, yacc[et]);
      }
    }
    asm volatile("" ::: "memory");
  }
  #pragma unroll
  for (int et = 0; et < 8; et++)
    #pragma unroll
    for (int r = 0; r < 4; r++)
      yp[((size_t)h * TT + rowbase + lg * 4 + r) * DH + et * 16 + l15] = yacc[et][r];
}

// ysh[h][t][0:128] = fp16(sum yp0..3); [128]=ent, [129]=dep, [130:192]=0
__global__ __launch_bounds__(256) void k_ysum(
    const float* __restrict__ yp0, const float* __restrict__ yp1,
    const float* __restrict__ yp2, const float* __restrict__ yp3,
    const float* __restrict__ ent, const float* __restrict__ dep,
    ushort_t* __restrict__ ysh) {
  int i = blockIdx.x * 256 + threadIdx.x;     // [0, 8*2048*16)
  int g = i & 15, t = (i >> 4) & 2047, h = i >> 15;
  size_t src = ((size_t)h * TT + t) * DH + g * 8;
  float4 a0 = *(const float4*)(yp0 + src);
  float4 a1 = *(const float4*)(yp1 + src);
  float4 a2 = *(const float4*)(yp2 + src);
  float4 a3 = *(const float4*)(yp3 + src);
  float4 b0 = *(const float4*)(yp0 + src + 4);
  float4 b1 = *(const float4*)(yp1 + src + 4);
  float4 b2 = *(const float4*)(yp2 + src + 4);
  float4 b3 = *(const float4*)(yp3 + src + 4);
  float s0 = (a0.x + a1.x) + (a2.x + a3.x);
  float s1 = (a0.y + a1.y) + (a2.y + a3.y);
  float s2 = (a0.z + a1.z) + (a2.z + a3.z);
  float s3 = (a0.w + a1.w) + (a2.w + a3.w);
  float s4 = (b0.x + b1.x) + (b2.x + b3.x);
  float s5 = (b0.y + b1.y) + (b2.y + b3.y);
  float s6 = (b0.z + b1.z) + (b2.z + b3.z);
  float s7 = (b0.w + b1.w) + (b2.w + b3.w);
  uintx4 o;
  o[0] = (unsigned)f2h(s0) | ((unsigned)f2h(s1) << 16);
  o[1] = (unsigned)f2h(s2) | ((unsigned)f2h(s3) << 16);
  o[2] = (unsigned)f2h(s4) | ((unsigned)f2h(s5) << 16);
  o[3] = (unsigned)f2h(s6) | ((unsigned)f2h(s7) << 16);
  ushort_t* row = ysh + ((size_t)h * TT + t) * 192;
  *(uintx4*)(row + g * 8) = o;
  if (g == 0) {
    uint2 cz;
    cz.x = (unsigned)f2h(ent[h * TT + t]) | ((unsigned)f2h(dep[h * TT + t]) << 16);
    cz.y = 0u;
    *(uint2*)(row + 128) = cz;
    uint2 z2; z2.x = 0u; z2.y = 0u;
    #pragma unroll
    for (int q = 132; q < 192; q += 4) *(uint2*)(row + q) = z2;
  }
}

extern "C" void kernel_launch(void* const* d_in, const int* in_sizes, int n_in,
                              void* d_out, int out_size, void* d_ws, size_t ws_size,
                              hipStream_t stream) {
  const float* x  = (const float*)d_in[0];
  const float* Wq = (const float*)d_in[1];
  const float* Wk = (const float*)d_in[2];
  const float* Wv = (const float*)d_in[3];
  const float* W2 = (const float*)d_in[4];
  const float* Wo = (const float*)d_in[5];
  float* out  = (float*)d_out;                  // [T,1024]
  float* out2 = out + (size_t)TT * 1024;        // att_win[-1] [T,T]
  float* ws = (float*)d_ws;

  ushort_t* xf   = (ushort_t*)(ws + F_XF);
  ushort_t* Uf   = (ushort_t*)(ws + F_UF);
  ushort_t* Qf   = (ushort_t*)(ws + F_QF);
  ushort_t* Kf   = (ushort_t*)(ws + F_KF);
  ushort_t* Vbf  = (ushort_t*)(ws + F_VBF);
  ushort_t* VT   = (ushort_t*)(ws + F_VT);
  ushort_t* ycf  = (ushort_t*)(ws + F_YCF);
  ushort_t* Wcat = (ushort_t*)(ws + F_WCAT);
  ushort_t* Wof  = (ushort_t*)(ws + F_WOF);
  ushort_t* W2f  = (ushort_t*)(ws + F_W2F);
  ushort_t* APh  = (ushort_t*)(ws + F_APH);
  ushort_t* ysh  = (ushort_t*)(ws + F_YSH);
  float*    Cm   = ws + F_C;
  float* divsum = ws + F_DIVS;
  float* Mst    = ws + F_MST;
  float* Lst    = ws + F_LST;
  float* entraw = ws + F_ENTR;
  float* ent    = ws + F_ENT;
  float* dep    = ws + F_DEP;
  float* Mp     = ws + F_MP;
  float* Lp     = ws + F_LP;
  float* sap    = ws + F_SAP;
  float* scp    = ws + F_SCP;
  float* yp0    = ws + F_YP0;
  float* yp1    = ws + F_YP1;
  float* yp2    = ws + F_YP2;
  float* yp3    = ws + F_YP3;

  k_tof16<<<2048, 256, 0, stream>>>(x, xf, 524288);
  k_rownorm_f16<<<TT, 256, 0, stream>>>(x, Uf);
  k_tof16<<<1024, 256, 0, stream>>>(Wq, Wcat, 262144);
  k_tof16<<<1024, 256, 0, stream>>>(Wk, Wcat + 1048576, 262144);
  k_tof16<<<1024, 256, 0, stream>>>(Wv, Wcat + 2097152, 262144);
  k_tof16<<<1024, 256, 0, stream>>>(Wo, Wof, 262144);
  k_w2pad<<<96, 256, 0, stream>>>(W2, W2f);

  k_gemm<0><<<dim3(16, 16), 256, 0, stream>>>(Uf, Uf, Cm, nullptr,
                                              nullptr, nullptr, nullptr, TT, TT, 1024);
  k_gemm<3><<<dim3(24, 16), 256, 0, stream>>>(xf, Wcat, nullptr, nullptr,
                                              Qf, Kf, Vbf, TT, 3072, 1024);

  k_divsum<<<TT, 256, 0, stream>>>(Cm, divsum);
  k_aph<<<TT, 256, 0, stream>>>(APh);

  k_phase1m<<<dim3(16, NH, 4), 512, 0, stream>>>(Qf, Kf, APh, Cm, Mp, Lp, sap, scp);
  k_combine<<<64, 256, 0, stream>>>(Mp, Lp, sap, scp, divsum, Mst, Lst, entraw, dep);
  k_entnorm<<<NH, 256, 0, stream>>>(entraw, ent);
  k_vprime<<<dim3(32, NH), 256, 0, stream>>>(Vbf, dep, VT);
  k_phase2m<<<dim3(16, NH, 4), 512, 0, stream>>>(Qf, Kf, APh, VT, Mst, Lst, dep,
                                                 yp0, yp1, yp2, yp3, out2);
  k_ysum<<<1024, 256, 0, stream>>>(yp0, yp1, yp2, yp3, ent, dep, ysh);
  k_gemm<4><<<dim3(1, 128), 256, 0, stream>>>(ysh, W2f, nullptr, ycf,
                                              nullptr, nullptr, nullptr, 16384, 128, 192);
  k_gemm<0><<<dim3(8, 16), 256, 0, stream>>>(ycf, Wof, out, nullptr,
                                             nullptr, nullptr, nullptr, TT, 1024, 1024);
}